// Round 9
// baseline (642.430 us; speedup 1.0000x reference)
//
#include <hip/hip_runtime.h>
#include <stdint.h>

#define NV 2097152
#define MC 1048576
#define EE 6291456
#define TT 10

#define CHUNK 8192
#define NBLK 768        // EE / CHUNK
#define FBK 512         // check blocks: 2048 checks = 12288 positions each
#define CPB 2048
#define CSEG 12288
#define FG 512          // forward groups: 4096 vars = 12288 edges each
#define GSEG 12288
#define VBK 512         // var blocks: 4096 vars = 12288 edge-nibbles each
#define VSEG 12288

// ---------------- cursor init: gcur[b] = b*12288 for both bin passes ----------------
__global__ __launch_bounds__(512) void initcur_kernel(uint32_t* __restrict__ gcur) {
    int i = blockIdx.x * 512 + threadIdx.x;     // grid 2x512 -> 1024
    gcur[i] = (uint32_t)(i & 511) * 12288u;
}

// ---------------- bin1: bucket edges by check-block, dest-sorted; 512 threads ----------------
__global__ __launch_bounds__(512) void bin1_kernel(const int* __restrict__ chk_idx,
                                                   uint32_t* __restrict__ gcurA,
                                                   uint32_t* __restrict__ im1_e,
                                                   uint16_t* __restrict__ im1_c) {
    __shared__ uint32_t cnt0[512];     // 2 KB
    __shared__ uint32_t aux[512];      // 2 KB: counts -> scan -> adj
    __shared__ uint32_t sA[CHUNK];     // 32 KB: (b<<23)|e
    __shared__ uint16_t sB[CHUNK];     // 16 KB: clow
    const int tid = threadIdx.x;
    const int rep = tid >> 8;
    const int base = blockIdx.x * CHUNK;
    cnt0[tid] = 0; aux[tid] = 0;
    __syncthreads();
    int4 cc4[4];
#pragma unroll
    for (int k = 0; k < 4; ++k) cc4[k] = ((const int4*)chk_idx)[(base >> 2) + tid + 512 * k];
    uint32_t br[16];                   // (b<<13)|rank
#pragma unroll
    for (int k = 0; k < 4; ++k) {
        int cv[4] = {cc4[k].x, cc4[k].y, cc4[k].z, cc4[k].w};
#pragma unroll
        for (int ii = 0; ii < 4; ++ii) {
            uint32_t b = (uint32_t)cv[ii] >> 11;
            uint32_t r = atomicAdd(rep ? &aux[b] : &cnt0[b], 1u);
            br[k * 4 + ii] = (b << 13) | r;
        }
    }
    __syncthreads();
    const uint32_t s0 = cnt0[tid] + aux[tid];
    aux[tid] = s0;
    __syncthreads();
    for (int d = 1; d < 512; d <<= 1) {
        uint32_t a0 = (tid >= d) ? aux[tid - d] : 0u;
        __syncthreads();
        aux[tid] += a0;
        __syncthreads();
    }
    const uint32_t excl0 = aux[tid] - s0;
    aux[tid] = excl0;
    const uint32_t gb0 = atomicAdd(&gcurA[tid], s0);
    __syncthreads();
#pragma unroll
    for (int k = 0; k < 4; ++k) {
        int cv[4] = {cc4[k].x, cc4[k].y, cc4[k].z, cc4[k].w};
#pragma unroll
        for (int ii = 0; ii < 4; ++ii) {
            uint32_t v = br[k * 4 + ii];
            uint32_t b = v >> 13;
            uint32_t r = v & 8191u;
            uint32_t j = aux[b] + (rep ? cnt0[b] : 0u) + r;
            uint32_t e = (uint32_t)(base + (tid + 512 * k) * 4 + ii);
            sA[j] = (b << 23) | e;
            sB[j] = (uint16_t)((uint32_t)cv[ii] & 2047u);
        }
    }
    __syncthreads();
    aux[tid] = gb0 - excl0;            // adj
    __syncthreads();
#pragma unroll 8
    for (int k = 0; k < 16; ++k) {
        int j = tid + 512 * k;
        uint32_t v = sA[j];
        uint32_t b = v >> 23;
        uint32_t addr = aux[b] + (uint32_t)j;
        im1_e[addr] = v & 0x7FFFFFu;
        im1_c[addr] = sB[j];
    }
}

// ---------------- place1 + ba fused; 1024 threads; backward keyed by 4096-var blocks ----------------
__global__ __launch_bounds__(1024) void place1_kernel(const uint32_t* __restrict__ im1_e,
                                                      const uint16_t* __restrict__ im1_c,
                                                      uint32_t* __restrict__ chk_edges,
                                                      uint8_t* __restrict__ b1rank,
                                                      uint32_t* __restrict__ runcntB) {
    __shared__ uint32_t win[CSEG];       // 48 KB
    __shared__ uint32_t ccnt[CPB / 2];   // 4 KB packed
    __shared__ uint32_t cntB[VBK];       // 2 KB
    const int tid = threadIdx.x, blk = blockIdx.x;
    ccnt[tid] = 0;                       // CPB/2 == 1024
    if (tid < VBK) cntB[tid] = 0;
    __syncthreads();
    const size_t cb = (size_t)blk * CSEG;
    for (int k = 0; k < 3; ++k) {
        int j0 = (tid + 1024 * k) * 4;
        const uint4 e4 = *(const uint4*)&im1_e[cb + j0];
        const ushort4 c4 = *(const ushort4*)&im1_c[cb + j0];
        uint32_t c, old, s;
        c = c4.x; old = atomicAdd(&ccnt[c >> 1], 1u << ((c & 1) * 16));
        s = (old >> ((c & 1) * 16)) & 0xFFFFu; win[c * 6 + s] = e4.x;
        c = c4.y; old = atomicAdd(&ccnt[c >> 1], 1u << ((c & 1) * 16));
        s = (old >> ((c & 1) * 16)) & 0xFFFFu; win[c * 6 + s] = e4.y;
        c = c4.z; old = atomicAdd(&ccnt[c >> 1], 1u << ((c & 1) * 16));
        s = (old >> ((c & 1) * 16)) & 0xFFFFu; win[c * 6 + s] = e4.z;
        c = c4.w; old = atomicAdd(&ccnt[c >> 1], 1u << ((c & 1) * 16));
        s = (old >> ((c & 1) * 16)) & 0xFFFFu; win[c * 6 + s] = e4.w;
    }
    __syncthreads();
    for (int j = tid; j < CSEG; j += 1024) chk_edges[cb + j] = win[j];
    for (int k = 0; k < CSEG / 1024; ++k) {
        int lp = tid + 1024 * k;
        uint32_t e = win[lp];
        uint32_t bB = (e / 3u) >> 12;    // 4096-var blocks
        uint32_t r = atomicAdd(&cntB[bB], 1u);
        b1rank[cb + lp] = (uint8_t)r;    // max count ~55, safe
    }
    __syncthreads();
    if (tid < VBK) runcntB[(size_t)tid * FBK + blk] = cntB[tid];
}

// ---------------- bin2: bucket (position -> edge) by var-group; 512 threads ----------------
__global__ __launch_bounds__(512) void bin2_kernel(const uint32_t* __restrict__ chk_edges,
                                                   uint32_t* __restrict__ gcurB,
                                                   uint32_t* __restrict__ im2_pay,
                                                   uint16_t* __restrict__ im2_el) {
    __shared__ uint32_t cnt0[512];
    __shared__ uint32_t aux[512];
    __shared__ uint32_t sA[CHUNK];     // (vb<<13)|pos_local
    __shared__ uint16_t sB[CHUNK];     // elow
    const int tid = threadIdx.x;
    const int rep = tid >> 8;
    const int base = blockIdx.x * CHUNK;
    cnt0[tid] = 0; aux[tid] = 0;
    __syncthreads();
    uint4 ee4[4];
#pragma unroll
    for (int k = 0; k < 4; ++k) ee4[k] = ((const uint4*)chk_edges)[(base >> 2) + tid + 512 * k];
    uint32_t br[16];
#pragma unroll
    for (int k = 0; k < 4; ++k) {
        uint32_t ev[4] = {ee4[k].x, ee4[k].y, ee4[k].z, ee4[k].w};
#pragma unroll
        for (int ii = 0; ii < 4; ++ii) {
            uint32_t vb = ev[ii] / 12288u;
            uint32_t r = atomicAdd(rep ? &aux[vb] : &cnt0[vb], 1u);
            br[k * 4 + ii] = (vb << 13) | r;
        }
    }
    __syncthreads();
    const uint32_t s0 = cnt0[tid] + aux[tid];
    aux[tid] = s0;
    __syncthreads();
    for (int d = 1; d < 512; d <<= 1) {
        uint32_t a0 = (tid >= d) ? aux[tid - d] : 0u;
        __syncthreads();
        aux[tid] += a0;
        __syncthreads();
    }
    const uint32_t excl0 = aux[tid] - s0;
    aux[tid] = excl0;
    const uint32_t gb0 = atomicAdd(&gcurB[tid], s0);
    __syncthreads();
#pragma unroll
    for (int k = 0; k < 4; ++k) {
        uint32_t ev[4] = {ee4[k].x, ee4[k].y, ee4[k].z, ee4[k].w};
#pragma unroll
        for (int ii = 0; ii < 4; ++ii) {
            uint32_t v = br[k * 4 + ii];
            uint32_t vb = v >> 13;
            uint32_t r = v & 8191u;
            uint32_t j = aux[vb] + (rep ? cnt0[vb] : 0u) + r;
            uint32_t pl = (uint32_t)((tid + 512 * k) * 4 + ii);
            sA[j] = (vb << 13) | pl;
            sB[j] = (uint16_t)(ev[ii] - vb * 12288u);
        }
    }
    __syncthreads();
    aux[tid] = gb0 - excl0;            // adj
    __syncthreads();
#pragma unroll 8
    for (int k = 0; k < 16; ++k) {
        int j = tid + 512 * k;
        uint32_t v = sA[j];
        uint32_t vb = v >> 13;
        uint32_t pos = (uint32_t)base + (v & 8191u);
        uint32_t c = pos / 6u;
        uint32_t s = pos - c * 6u;
        uint32_t addr = aux[vb] + (uint32_t)j;
        im2_pay[addr] = (c << 3) | s;
        im2_el[addr] = sB[j];
    }
}

// ---------------- place2 + fa fused; 1024 threads ----------------
__global__ __launch_bounds__(1024) void place2_kernel(const uint32_t* __restrict__ im2_pay,
                                                      const uint16_t* __restrict__ im2_el,
                                                      uint32_t* __restrict__ dest,
                                                      uint8_t* __restrict__ f1rank,
                                                      uint32_t* __restrict__ runcntF) {
    __shared__ uint32_t win2[GSEG];      // 48 KB
    __shared__ uint32_t cntF[FBK];       // 2 KB
    const int tid = threadIdx.x, g = blockIdx.x;
    if (tid < FBK) cntF[tid] = 0;
    __syncthreads();
    const size_t gb = (size_t)g * GSEG;
    for (int k = 0; k < 3; ++k) {
        int j0 = (tid + 1024 * k) * 4;
        const uint4 p4 = *(const uint4*)&im2_pay[gb + j0];
        const ushort4 e4 = *(const ushort4*)&im2_el[gb + j0];
        win2[e4.x] = p4.x; win2[e4.y] = p4.y; win2[e4.z] = p4.z; win2[e4.w] = p4.w;
    }
    __syncthreads();
    for (int j = tid; j < GSEG; j += 1024) dest[gb + j] = win2[j];
    for (int k = 0; k < GSEG / 1024; ++k) {
        int le = tid + 1024 * k;
        uint32_t b = (win2[le] >> 3) >> 11;
        uint32_t r = atomicAdd(&cntF[b], 1u);
        f1rank[gb + le] = (uint8_t)r;
    }
    __syncthreads();
    if (tid < FBK) runcntF[(size_t)tid * FG + g] = cntF[tid];
}

// ---------------- scans (parallel: one block per row, LDS block-scan) ----------------
__global__ __launch_bounds__(256) void scanF_kernel(const uint32_t* __restrict__ runcntF,
                                                    uint32_t* __restrict__ f1base) {
    __shared__ uint32_t sc[512];
    const int tid = threadIdx.x, b = blockIdx.x;     // grid FBK
    uint32_t c0 = runcntF[(size_t)b * FG + tid];
    uint32_t c1 = runcntF[(size_t)b * FG + tid + 256];
    sc[tid] = c0; sc[tid + 256] = c1;
    __syncthreads();
    for (int d = 1; d < 512; d <<= 1) {
        uint32_t a0 = (tid >= d) ? sc[tid - d] : 0u;
        uint32_t a1 = sc[tid + 256 - d];
        __syncthreads();
        sc[tid] += a0; sc[tid + 256] += a1;
        __syncthreads();
    }
    uint32_t base = (uint32_t)b * CSEG;
    f1base[(size_t)tid * FBK + b] = base + sc[tid] - c0;
    f1base[(size_t)(tid + 256) * FBK + b] = base + sc[tid + 256] - c1;
}

__global__ __launch_bounds__(256) void scanB_kernel(const uint32_t* __restrict__ runcntB,
                                                    uint32_t* __restrict__ b1base) {
    __shared__ uint32_t sc[512];
    const int tid = threadIdx.x, bB = blockIdx.x;    // grid VBK=512
    uint32_t c0 = runcntB[(size_t)bB * FBK + tid];
    uint32_t c1 = runcntB[(size_t)bB * FBK + tid + 256];
    sc[tid] = c0; sc[tid + 256] = c1;
    __syncthreads();
    for (int d = 1; d < 512; d <<= 1) {
        uint32_t a0 = (tid >= d) ? sc[tid - d] : 0u;
        uint32_t a1 = sc[tid + 256 - d];
        __syncthreads();
        sc[tid] += a0; sc[tid + 256] += a1;
        __syncthreads();
    }
    uint32_t base = (uint32_t)bB * VSEG;
    b1base[(size_t)tid * VBK + bB] = base + sc[tid] - c0;
    b1base[(size_t)(tid + 256) * VBK + bB] = base + sc[tid + 256] - c1;
}

// ---------------- fb: forward sorted tables; 1024 threads ----------------
// lvF packs (lv<<2)|slot so var can compute per-edge v2c at scatter time.
__global__ __launch_bounds__(1024) void fb_kernel(const uint32_t* __restrict__ dest,
                                                  const uint8_t* __restrict__ f1rank,
                                                  const uint32_t* __restrict__ runcntF,
                                                  const uint32_t* __restrict__ f1base,
                                                  uint32_t* __restrict__ goffF,
                                                  uint16_t* __restrict__ f2pos,
                                                  uint16_t* __restrict__ bidxF,
                                                  uint16_t* __restrict__ lvF) {
    __shared__ uint32_t flb[FBK];        // 2 KB
    __shared__ uint32_t rowf[FBK];       // 2 KB
    __shared__ uint32_t sortv[GSEG];     // 48 KB
    const int tid = threadIdx.x, g = blockIdx.x;
    uint32_t c0 = 0;
    if (tid < FBK) {
        c0 = runcntF[(size_t)tid * FG + g];
        flb[tid] = c0;
        rowf[tid] = f1base[(size_t)g * FBK + tid];
    }
    __syncthreads();
    for (int d = 1; d < FBK; d <<= 1) {
        uint32_t a0 = 0;
        if (tid < FBK) a0 = (tid >= d) ? flb[tid - d] : 0u;
        __syncthreads();
        if (tid < FBK) flb[tid] += a0;
        __syncthreads();
    }
    if (tid < FBK) flb[tid] -= c0;
    __syncthreads();
    if (tid < FBK) goffF[(size_t)g * FBK + tid] = rowf[tid] - flb[tid];
    const size_t gb = (size_t)g * GSEG;
    // round 1: f2pos + bidxF
    for (int k = 0; k < GSEG / 1024; ++k) {
        int le = tid + 1024 * k;
        uint32_t d = dest[gb + le];
        uint32_t r = f1rank[gb + le];
        uint32_t c = d >> 3;
        uint32_t b = c >> 11;
        uint32_t pl = c * 6u + (d & 7u) - b * 12288u;
        sortv[flb[b] + r] = (b << 14) | pl;
    }
    __syncthreads();
    for (int k = 0; k < GSEG / 1024; ++k) {
        int j = tid + 1024 * k;
        uint32_t v = sortv[j];
        uint32_t b = v >> 14;
        f2pos[rowf[b] - flb[b] + j] = (uint16_t)(v & 16383u);
        bidxF[gb + j] = (uint16_t)b;
    }
    __syncthreads();
    // round 2: lvF = (lv<<2)|slot
    for (int k = 0; k < GSEG / 1024; ++k) {
        int le = tid + 1024 * k;
        uint32_t d = dest[gb + le];
        uint32_t r = f1rank[gb + le];
        uint32_t b = (d >> 3) >> 11;
        uint32_t lv = (uint32_t)(le / 3);
        uint32_t sl = (uint32_t)le - 3u * lv;
        sortv[flb[b] + r] = (lv << 2) | sl;
    }
    __syncthreads();
    for (int k = 0; k < GSEG / 1024; ++k) {
        int j = tid + 1024 * k;
        lvF[gb + j] = (uint16_t)sortv[j];
    }
}

// ---------------- bb: backward sorted tables; 1024 threads; bwd packs (bB<<14)|lp ----------------
__global__ __launch_bounds__(1024) void bb_kernel(const uint32_t* __restrict__ chk_edges,
                                                  const uint8_t* __restrict__ b1rank,
                                                  const uint32_t* __restrict__ runcntB,
                                                  const uint32_t* __restrict__ b1base,
                                                  uint32_t* __restrict__ goffB,
                                                  uint16_t* __restrict__ b2pos,
                                                  uint32_t* __restrict__ bwd) {
    __shared__ uint32_t blb[VBK];        // 2 KB
    __shared__ uint32_t rowb[VBK];       // 2 KB
    __shared__ uint32_t sortv[CSEG];     // 48 KB
    const int tid = threadIdx.x, blk = blockIdx.x;
    uint32_t c0 = 0;
    if (tid < VBK) {
        c0 = runcntB[(size_t)tid * FBK + blk];
        blb[tid] = c0;
        rowb[tid] = b1base[(size_t)blk * VBK + tid];
    }
    __syncthreads();
    for (int d = 1; d < VBK; d <<= 1) {
        uint32_t a0 = 0;
        if (tid < VBK) a0 = (tid >= d) ? blb[tid - d] : 0u;
        __syncthreads();
        if (tid < VBK) blb[tid] += a0;
        __syncthreads();
    }
    if (tid < VBK) blb[tid] -= c0;
    __syncthreads();
    if (tid < VBK) goffB[(size_t)blk * VBK + tid] = rowb[tid] - blb[tid];
    const size_t cb = (size_t)blk * CSEG;
    // round 1: b2pos (var-keyed nibble index)
    for (int k = 0; k < CSEG / 1024; ++k) {
        int lp = tid + 1024 * k;
        uint32_t e = chk_edges[cb + lp];
        uint32_t r = b1rank[cb + lp];
        uint32_t bB = (e / 3u) >> 12;
        uint32_t elocal = e - bB * VSEG;
        sortv[blb[bB] + r] = (bB << 14) | elocal;
    }
    __syncthreads();
    for (int k = 0; k < CSEG / 1024; ++k) {
        int j = tid + 1024 * k;
        uint32_t v = sortv[j];
        uint32_t bB = v >> 14;
        b2pos[rowb[bB] - blb[bB] + j] = (uint16_t)(v & 16383u);
    }
    __syncthreads();
    // round 2: bwd = (bB<<14)|lp in sorted order
    for (int k = 0; k < CSEG / 1024; ++k) {
        int lp = tid + 1024 * k;
        uint32_t e = chk_edges[cb + lp];
        uint32_t r = b1rank[cb + lp];
        uint32_t bB = (e / 3u) >> 12;
        sortv[blb[bB] + r] = (bB << 14) | (uint32_t)lp;
    }
    __syncthreads();
    for (int k = 0; k < CSEG / 1024; ++k) {
        int j = tid + 1024 * k;
        bwd[cb + j] = sortv[j];
    }
}

// ---------------- per-iteration check kernel; 1024 threads ----------------
__global__ __launch_bounds__(1024) void check_kernel(const float* __restrict__ finterm,
                                                     const uint16_t* __restrict__ f2pos,
                                                     const uint32_t* __restrict__ bwd,
                                                     const uint32_t* __restrict__ goffB,
                                                     uint8_t* __restrict__ binterm,
                                                     const float* __restrict__ beta,
                                                     const float* __restrict__ thresholds,
                                                     int t) {
    __shared__ __align__(16) float fwin[CSEG];   // 48 KB; front 8 KB reused as ewin
    __shared__ uint32_t grow[VBK];               // 2 KB
    uint32_t* ewin = (uint32_t*)fwin;
    const int tid = threadIdx.x, blk = blockIdx.x;
    if (tid < VBK) grow[tid] = goffB[(size_t)blk * VBK + tid];
    const size_t cb = (size_t)blk * CSEG;
    for (int k = 0; k < 3; ++k) {
        int j0 = (tid + 1024 * k) * 4;
        const float4 f4 = *(const float4*)&finterm[cb + j0];
        const ushort4 p4 = *(const ushort4*)&f2pos[cb + j0];
        fwin[p4.x] = f4.x; fwin[p4.y] = f4.y; fwin[p4.z] = f4.z; fwin[p4.w] = f4.w;
    }
    __syncthreads();

    const float b = beta[t];
    const float* thc = thresholds + t * 8;
    const float th1 = thc[1], th2 = thc[2], th3 = thc[3], th4 = thc[4];
    const float th5 = thc[5], th6 = thc[6], th7 = thc[7];
    const uint32_t signb = (b < 0.0f) ? 1u : 0u;

    uint32_t wreg[2];
    for (int i = 0; i < 2; ++i) {
        int lc = tid + 1024 * i;
        float mags[6];
        uint32_t sgn[6];
        uint32_t parity = 0;
        uint64_t minkey = ~0ull;
#pragma unroll
        for (int j = 0; j < 6; ++j) {
            float x = fwin[lc * 6 + j];            // v2c directly
            uint32_t s = (x < 0.0f) ? 1u : 0u;
            parity ^= s;
            sgn[j] = s;
            float mg = fabsf(x);
            mags[j] = mg;
            uint64_t key = (((uint64_t)__float_as_uint(mg)) << 3) | (uint32_t)j;
            minkey = (key < minkey) ? key : minkey;
        }
        float min1 = __uint_as_float((uint32_t)(minkey >> 3));
        uint32_t fs = (uint32_t)(minkey & 7u);
        float min2 = INFINITY;
#pragma unroll
        for (int j = 0; j < 6; ++j) {
            if ((uint32_t)j != fs) min2 = fminf(min2, mags[j]);
        }
        float m1 = fabsf(b * min1);
        float m2 = fabsf(b * min2);
        uint32_t q1 = (uint32_t)(m1 >= th1) + (uint32_t)(m1 >= th2) + (uint32_t)(m1 >= th3)
                    + (uint32_t)(m1 >= th4) + (uint32_t)(m1 >= th5) + (uint32_t)(m1 >= th6)
                    + (uint32_t)(m1 >= th7);
        uint32_t q2 = (uint32_t)(m2 >= th1) + (uint32_t)(m2 >= th2) + (uint32_t)(m2 >= th3)
                    + (uint32_t)(m2 >= th4) + (uint32_t)(m2 >= th5) + (uint32_t)(m2 >= th6)
                    + (uint32_t)(m2 >= th7);
        uint32_t w = 0;
#pragma unroll
        for (int j = 0; j < 6; ++j) {
            uint32_t neg = signb ^ parity ^ sgn[j];
            uint32_t q = ((uint32_t)j == fs) ? q2 : q1;
            w |= ((neg << 3) | q) << (4 * j);
        }
        wreg[i] = w;
    }
    __syncthreads();                 // fwin reads done; safe to alias ewin
    for (int i = 0; i < 2; ++i) {
        int lc = tid + 1024 * i;
        ewin[lc] = wreg[i];
    }
    __syncthreads();
    for (int k = 0; k < 3; ++k) {
        int j0 = (tid + 1024 * k) * 4;
        const uint4 w4 = *(const uint4*)&bwd[cb + j0];
        uint32_t w, lp, word;
        w = w4.x; lp = w & 16383u; word = ewin[lp / 6u];
        binterm[grow[w >> 14] + j0 + 0] = (uint8_t)((word >> ((lp - 6u * (lp / 6u)) * 4u)) & 15u);
        w = w4.y; lp = w & 16383u; word = ewin[lp / 6u];
        binterm[grow[w >> 14] + j0 + 1] = (uint8_t)((word >> ((lp - 6u * (lp / 6u)) * 4u)) & 15u);
        w = w4.z; lp = w & 16383u; word = ewin[lp / 6u];
        binterm[grow[w >> 14] + j0 + 2] = (uint8_t)((word >> ((lp - 6u * (lp / 6u)) * 4u)) & 15u);
        w = w4.w; lp = w & 16383u; word = ewin[lp / 6u];
        binterm[grow[w >> 14] + j0 + 3] = (uint8_t)((word >> ((lp - 6u * (lp / 6u)) * 4u)) & 15u);
    }
}

// ---------------- per-iteration variable kernel; grid 512 x 1024, 2 blocks/CU ----------------
// 4096 vars/block; one forward group per block (no h-loop). LDS ~31 KB.
// Scatter writes per-edge v2c = alpha[t]*(post - c2v_edge) — bit-identical chain.
__global__ __launch_bounds__(1024, 8) void var_kernel(const float* __restrict__ llr,
                                                      const uint8_t* __restrict__ binterm,
                                                      const uint16_t* __restrict__ b2pos,
                                                      const uint16_t* __restrict__ lvF,
                                                      const uint16_t* __restrict__ bidxF,
                                                      const uint32_t* __restrict__ goffF,
                                                      float* __restrict__ finterm,
                                                      const float* __restrict__ thresholds,
                                                      const float* __restrict__ alpha,
                                                      int t, int mode,
                                                      float* __restrict__ out) {
    __shared__ uint8_t nwin[VSEG];       // 12 KB
    __shared__ float pwin[4096];         // 16 KB
    __shared__ uint32_t growF[FBK];      // 2 KB
    __shared__ float tl[8];
    const int tid = threadIdx.x, vblk = blockIdx.x;   // grid VBK=512
    if (tid < 8) tl[tid] = thresholds[t * 8 + tid];
    if (mode != 1) {
        const size_t vb = (size_t)vblk * VSEG;
        for (int k = 0; k < 3; ++k) {
            int i0 = (tid + 1024 * k) * 4;
            const uchar4 n4 = *(const uchar4*)&binterm[vb + i0];
            const ushort4 p4 = *(const ushort4*)&b2pos[vb + i0];
            nwin[p4.x] = n4.x; nwin[p4.y] = n4.y; nwin[p4.z] = n4.z; nwin[p4.w] = n4.w;
        }
    }
    __syncthreads();
    const float a = (mode == 1) ? 1.0f : alpha[t];
    for (int i = 0; i < 4; ++i) {
        int lv = tid + 1024 * i;
        int v = vblk * 4096 + lv;
        float post;
        if (mode == 1) {
            post = llr[v];
        } else {
            uint32_t n0 = nwin[3 * lv], n1 = nwin[3 * lv + 1], n2 = nwin[3 * lv + 2];
            float c0 = (n0 & 8u) ? -tl[n0 & 7u] : tl[n0 & 7u];
            float c1 = (n1 & 8u) ? -tl[n1 & 7u] : tl[n1 & 7u];
            float c2 = (n2 & 8u) ? -tl[n2 & 7u] : tl[n2 & 7u];
            post = llr[v] + ((c0 + c1) + c2);      // reference summation order
        }
        pwin[lv] = post;
        if (mode == 2) {
            out[v] = (post < 0.0f) ? 1.0f : 0.0f;
            out[NV + v] = post;
            if (v == 0) out[2 * NV] = 10.0f;
        }
    }
    if (mode == 2) return;                         // uniform across block
    if (tid < FBK) growF[tid] = goffF[(size_t)vblk * FBK + tid];
    __syncthreads();                               // pwin + growF ready
    const size_t gb = (size_t)vblk * GSEG;
    for (int k = 0; k < 3; ++k) {
        int j0 = (tid + 1024 * k) * 4;
        const ushort4 lv4 = *(const ushort4*)&lvF[gb + j0];
        const ushort4 b4 = *(const ushort4*)&bidxF[gb + j0];
        float v0, v1, v2, v3;
        if (mode == 1) {
            v0 = pwin[lv4.x >> 2]; v1 = pwin[lv4.y >> 2];
            v2 = pwin[lv4.z >> 2]; v3 = pwin[lv4.w >> 2];
        } else {
            uint32_t e, lvq, nib; float c;
            e = lv4.x; lvq = e >> 2; nib = nwin[3 * lvq + (e & 3u)];
            c = (nib & 8u) ? -tl[nib & 7u] : tl[nib & 7u];
            v0 = a * (pwin[lvq] - c);
            e = lv4.y; lvq = e >> 2; nib = nwin[3 * lvq + (e & 3u)];
            c = (nib & 8u) ? -tl[nib & 7u] : tl[nib & 7u];
            v1 = a * (pwin[lvq] - c);
            e = lv4.z; lvq = e >> 2; nib = nwin[3 * lvq + (e & 3u)];
            c = (nib & 8u) ? -tl[nib & 7u] : tl[nib & 7u];
            v2 = a * (pwin[lvq] - c);
            e = lv4.w; lvq = e >> 2; nib = nwin[3 * lvq + (e & 3u)];
            c = (nib & 8u) ? -tl[nib & 7u] : tl[nib & 7u];
            v3 = a * (pwin[lvq] - c);
        }
        finterm[growF[b4.x] + j0 + 0] = v0;
        finterm[growF[b4.y] + j0 + 1] = v1;
        finterm[growF[b4.z] + j0 + 2] = v2;
        finterm[growF[b4.w] + j0 + 3] = v3;
    }
}

extern "C" void kernel_launch(void* const* d_in, const int* in_sizes, int n_in,
                              void* d_out, int out_size, void* d_ws, size_t ws_size,
                              hipStream_t stream) {
    const float* llr        = (const float*)d_in[0];
    const int*   var_idx    = (const int*)d_in[1];   (void)var_idx;   // implicit e/3
    const int*   chk_idx    = (const int*)d_in[2];
    const float* beta       = (const float*)d_in[3];
    const float* alpha      = (const float*)d_in[4];
    const float* thresholds = (const float*)d_in[5];
    float* out = (float*)d_out;

    // workspace layout (~214 MB; im2 aliases im1 — im1 dead after place1)
    char* wsb = (char*)d_ws;
    float*    finterm   = (float*)(wsb + 0);                  // 25165824
    uint16_t* f2pos     = (uint16_t*)(wsb + 25165824);        // 12582912
    uint16_t* lvF       = (uint16_t*)(wsb + 37748736);        // 12582912
    uint16_t* bidxF     = (uint16_t*)(wsb + 50331648);        // 12582912
    uint32_t* bwd       = (uint32_t*)(wsb + 62914560);        // 25165824
    uint16_t* b2pos     = (uint16_t*)(wsb + 88080384);        // 12582912
    uint8_t*  binterm   = (uint8_t*)(wsb + 100663296);        // 6291456
    uint32_t* chk_edges = (uint32_t*)(wsb + 106954752);       // 25165824
    uint32_t* dest      = (uint32_t*)(wsb + 132120576);       // 25165824
    uint32_t* im1_e     = (uint32_t*)(wsb + 157286400);       // 25165824
    uint16_t* im1_c     = (uint16_t*)(wsb + 182452224);       // 12582912
    uint32_t* im2_pay   = im1_e;                              // alias (im1 dead)
    uint16_t* im2_el    = im1_c;                              // alias
    uint8_t*  f1rank    = (uint8_t*)(wsb + 195035136);        // 6291456
    uint8_t*  b1rank    = (uint8_t*)(wsb + 201326592);        // 6291456
    uint32_t* runcntF   = (uint32_t*)(wsb + 207618048);       // 1048576
    uint32_t* f1base    = (uint32_t*)(wsb + 208666624);       // 1048576
    uint32_t* runcntB   = (uint32_t*)(wsb + 209715200);       // 1048576
    uint32_t* b1base    = (uint32_t*)(wsb + 210763776);       // 1048576
    uint32_t* goffF     = (uint32_t*)(wsb + 211812352);       // 1048576
    uint32_t* goffB     = (uint32_t*)(wsb + 212860928);       // 1048576
    uint32_t* gcur      = (uint32_t*)(wsb + 213909504);       // 4096
    uint32_t* gcurA     = gcur;
    uint32_t* gcurB     = gcur + 512;

    initcur_kernel<<<2, 512, 0, stream>>>(gcur);
    bin1_kernel<<<NBLK, 512, 0, stream>>>(chk_idx, gcurA, im1_e, im1_c);
    place1_kernel<<<FBK, 1024, 0, stream>>>(im1_e, im1_c, chk_edges, b1rank, runcntB);
    bin2_kernel<<<NBLK, 512, 0, stream>>>(chk_edges, gcurB, im2_pay, im2_el);
    place2_kernel<<<FG, 1024, 0, stream>>>(im2_pay, im2_el, dest, f1rank, runcntF);
    scanF_kernel<<<FBK, 256, 0, stream>>>(runcntF, f1base);
    fb_kernel<<<FG, 1024, 0, stream>>>(dest, f1rank, runcntF, f1base, goffF, f2pos, bidxF, lvF);
    scanB_kernel<<<VBK, 256, 0, stream>>>(runcntB, b1base);
    bb_kernel<<<FBK, 1024, 0, stream>>>(chk_edges, b1rank, runcntB, b1base, goffB, b2pos, bwd);
    // seed: finterm <- llr (v2c_0) via forward permute (mode 1)
    var_kernel<<<VBK, 1024, 0, stream>>>(llr, binterm, b2pos, lvF, bidxF, goffF,
                                         finterm, thresholds, alpha, 0, 1, out);

    for (int t = 0; t < TT; ++t) {
        check_kernel<<<FBK, 1024, 0, stream>>>(finterm, f2pos, bwd, goffB,
                                               binterm, beta, thresholds, t);
        var_kernel<<<VBK, 1024, 0, stream>>>(llr, binterm, b2pos, lvF, bidxF, goffF,
                                             finterm, thresholds, alpha, t,
                                             (t == TT - 1) ? 2 : 0, out);
    }
}

// Round 10
// 638.197 us; speedup vs baseline: 1.0066x; 1.0066x over previous
//
#include <hip/hip_runtime.h>
#include <stdint.h>

#define NV 2097152
#define MC 1048576
#define EE 6291456
#define TT 10

#define CHUNK 8192
#define NBLK 768        // EE / CHUNK
#define FBK 512         // check blocks: 2048 checks = 12288 positions each
#define CPB 2048
#define CSEG 12288
#define FG 512          // forward groups: 4096 vars = 12288 edges each
#define GSEG 12288
#define VBK 512         // var blocks: 4096 vars = 12288 edge-nibbles each
#define VSEG 12288

// ---------------- cursor init: gcur[b] = b*12288 for both bin passes ----------------
__global__ __launch_bounds__(512) void initcur_kernel(uint32_t* __restrict__ gcur) {
    int i = blockIdx.x * 512 + threadIdx.x;     // grid 2x512 -> 1024
    gcur[i] = (uint32_t)(i & 511) * 12288u;
}

// ---------------- bin1: bucket edges by check-block, dest-sorted; 512 threads ----------------
__global__ __launch_bounds__(512) void bin1_kernel(const int* __restrict__ chk_idx,
                                                   uint32_t* __restrict__ gcurA,
                                                   uint32_t* __restrict__ im1_e,
                                                   uint16_t* __restrict__ im1_c) {
    __shared__ uint32_t cnt0[512];     // 2 KB
    __shared__ uint32_t aux[512];      // 2 KB: counts -> scan -> adj
    __shared__ uint32_t sA[CHUNK];     // 32 KB: (b<<23)|e
    __shared__ uint16_t sB[CHUNK];     // 16 KB: clow
    const int tid = threadIdx.x;
    const int rep = tid >> 8;
    const int base = blockIdx.x * CHUNK;
    cnt0[tid] = 0; aux[tid] = 0;
    __syncthreads();
    int4 cc4[4];
#pragma unroll
    for (int k = 0; k < 4; ++k) cc4[k] = ((const int4*)chk_idx)[(base >> 2) + tid + 512 * k];
    uint32_t br[16];                   // (b<<13)|rank
#pragma unroll
    for (int k = 0; k < 4; ++k) {
        int cv[4] = {cc4[k].x, cc4[k].y, cc4[k].z, cc4[k].w};
#pragma unroll
        for (int ii = 0; ii < 4; ++ii) {
            uint32_t b = (uint32_t)cv[ii] >> 11;
            uint32_t r = atomicAdd(rep ? &aux[b] : &cnt0[b], 1u);
            br[k * 4 + ii] = (b << 13) | r;
        }
    }
    __syncthreads();
    const uint32_t s0 = cnt0[tid] + aux[tid];
    aux[tid] = s0;
    __syncthreads();
    for (int d = 1; d < 512; d <<= 1) {
        uint32_t a0 = (tid >= d) ? aux[tid - d] : 0u;
        __syncthreads();
        aux[tid] += a0;
        __syncthreads();
    }
    const uint32_t excl0 = aux[tid] - s0;
    aux[tid] = excl0;
    const uint32_t gb0 = atomicAdd(&gcurA[tid], s0);
    __syncthreads();
#pragma unroll
    for (int k = 0; k < 4; ++k) {
        int cv[4] = {cc4[k].x, cc4[k].y, cc4[k].z, cc4[k].w};
#pragma unroll
        for (int ii = 0; ii < 4; ++ii) {
            uint32_t v = br[k * 4 + ii];
            uint32_t b = v >> 13;
            uint32_t r = v & 8191u;
            uint32_t j = aux[b] + (rep ? cnt0[b] : 0u) + r;
            uint32_t e = (uint32_t)(base + (tid + 512 * k) * 4 + ii);
            sA[j] = (b << 23) | e;
            sB[j] = (uint16_t)((uint32_t)cv[ii] & 2047u);
        }
    }
    __syncthreads();
    aux[tid] = gb0 - excl0;            // adj
    __syncthreads();
#pragma unroll 8
    for (int k = 0; k < 16; ++k) {
        int j = tid + 512 * k;
        uint32_t v = sA[j];
        uint32_t b = v >> 23;
        uint32_t addr = aux[b] + (uint32_t)j;
        im1_e[addr] = v & 0x7FFFFFu;
        im1_c[addr] = sB[j];
    }
}

// ---------------- place1 + ba fused; 1024 threads; backward keyed by 4096-var blocks ----------------
__global__ __launch_bounds__(1024) void place1_kernel(const uint32_t* __restrict__ im1_e,
                                                      const uint16_t* __restrict__ im1_c,
                                                      uint32_t* __restrict__ chk_edges,
                                                      uint8_t* __restrict__ b1rank,
                                                      uint32_t* __restrict__ runcntB) {
    __shared__ uint32_t win[CSEG];       // 48 KB
    __shared__ uint32_t ccnt[CPB / 2];   // 4 KB packed
    __shared__ uint32_t cntB[VBK];       // 2 KB
    const int tid = threadIdx.x, blk = blockIdx.x;
    ccnt[tid] = 0;                       // CPB/2 == 1024
    if (tid < VBK) cntB[tid] = 0;
    __syncthreads();
    const size_t cb = (size_t)blk * CSEG;
    for (int k = 0; k < 3; ++k) {
        int j0 = (tid + 1024 * k) * 4;
        const uint4 e4 = *(const uint4*)&im1_e[cb + j0];
        const ushort4 c4 = *(const ushort4*)&im1_c[cb + j0];
        uint32_t c, old, s;
        c = c4.x; old = atomicAdd(&ccnt[c >> 1], 1u << ((c & 1) * 16));
        s = (old >> ((c & 1) * 16)) & 0xFFFFu; win[c * 6 + s] = e4.x;
        c = c4.y; old = atomicAdd(&ccnt[c >> 1], 1u << ((c & 1) * 16));
        s = (old >> ((c & 1) * 16)) & 0xFFFFu; win[c * 6 + s] = e4.y;
        c = c4.z; old = atomicAdd(&ccnt[c >> 1], 1u << ((c & 1) * 16));
        s = (old >> ((c & 1) * 16)) & 0xFFFFu; win[c * 6 + s] = e4.z;
        c = c4.w; old = atomicAdd(&ccnt[c >> 1], 1u << ((c & 1) * 16));
        s = (old >> ((c & 1) * 16)) & 0xFFFFu; win[c * 6 + s] = e4.w;
    }
    __syncthreads();
    for (int j = tid; j < CSEG; j += 1024) chk_edges[cb + j] = win[j];
    for (int k = 0; k < CSEG / 1024; ++k) {
        int lp = tid + 1024 * k;
        uint32_t e = win[lp];
        uint32_t bB = (e / 3u) >> 12;    // 4096-var blocks
        uint32_t r = atomicAdd(&cntB[bB], 1u);
        b1rank[cb + lp] = (uint8_t)r;    // max run count ~60, safe
    }
    __syncthreads();
    if (tid < VBK) runcntB[(size_t)tid * FBK + blk] = cntB[tid];
}

// ---------------- bin2: bucket (position -> edge) by var-group; 512 threads ----------------
__global__ __launch_bounds__(512) void bin2_kernel(const uint32_t* __restrict__ chk_edges,
                                                   uint32_t* __restrict__ gcurB,
                                                   uint32_t* __restrict__ im2_pay,
                                                   uint16_t* __restrict__ im2_el) {
    __shared__ uint32_t cnt0[512];
    __shared__ uint32_t aux[512];
    __shared__ uint32_t sA[CHUNK];     // (vb<<13)|pos_local
    __shared__ uint16_t sB[CHUNK];     // elow
    const int tid = threadIdx.x;
    const int rep = tid >> 8;
    const int base = blockIdx.x * CHUNK;
    cnt0[tid] = 0; aux[tid] = 0;
    __syncthreads();
    uint4 ee4[4];
#pragma unroll
    for (int k = 0; k < 4; ++k) ee4[k] = ((const uint4*)chk_edges)[(base >> 2) + tid + 512 * k];
    uint32_t br[16];
#pragma unroll
    for (int k = 0; k < 4; ++k) {
        uint32_t ev[4] = {ee4[k].x, ee4[k].y, ee4[k].z, ee4[k].w};
#pragma unroll
        for (int ii = 0; ii < 4; ++ii) {
            uint32_t vb = ev[ii] / 12288u;
            uint32_t r = atomicAdd(rep ? &aux[vb] : &cnt0[vb], 1u);
            br[k * 4 + ii] = (vb << 13) | r;
        }
    }
    __syncthreads();
    const uint32_t s0 = cnt0[tid] + aux[tid];
    aux[tid] = s0;
    __syncthreads();
    for (int d = 1; d < 512; d <<= 1) {
        uint32_t a0 = (tid >= d) ? aux[tid - d] : 0u;
        __syncthreads();
        aux[tid] += a0;
        __syncthreads();
    }
    const uint32_t excl0 = aux[tid] - s0;
    aux[tid] = excl0;
    const uint32_t gb0 = atomicAdd(&gcurB[tid], s0);
    __syncthreads();
#pragma unroll
    for (int k = 0; k < 4; ++k) {
        uint32_t ev[4] = {ee4[k].x, ee4[k].y, ee4[k].z, ee4[k].w};
#pragma unroll
        for (int ii = 0; ii < 4; ++ii) {
            uint32_t v = br[k * 4 + ii];
            uint32_t vb = v >> 13;
            uint32_t r = v & 8191u;
            uint32_t j = aux[vb] + (rep ? cnt0[vb] : 0u) + r;
            uint32_t pl = (uint32_t)((tid + 512 * k) * 4 + ii);
            sA[j] = (vb << 13) | pl;
            sB[j] = (uint16_t)(ev[ii] - vb * 12288u);
        }
    }
    __syncthreads();
    aux[tid] = gb0 - excl0;            // adj
    __syncthreads();
#pragma unroll 8
    for (int k = 0; k < 16; ++k) {
        int j = tid + 512 * k;
        uint32_t v = sA[j];
        uint32_t vb = v >> 13;
        uint32_t pos = (uint32_t)base + (v & 8191u);
        uint32_t c = pos / 6u;
        uint32_t s = pos - c * 6u;
        uint32_t addr = aux[vb] + (uint32_t)j;
        im2_pay[addr] = (c << 3) | s;
        im2_el[addr] = sB[j];
    }
}

// ---------------- place2 + fa fused; 1024 threads ----------------
__global__ __launch_bounds__(1024) void place2_kernel(const uint32_t* __restrict__ im2_pay,
                                                      const uint16_t* __restrict__ im2_el,
                                                      uint32_t* __restrict__ dest,
                                                      uint8_t* __restrict__ f1rank,
                                                      uint32_t* __restrict__ runcntF) {
    __shared__ uint32_t win2[GSEG];      // 48 KB
    __shared__ uint32_t cntF[FBK];       // 2 KB
    const int tid = threadIdx.x, g = blockIdx.x;
    if (tid < FBK) cntF[tid] = 0;
    __syncthreads();
    const size_t gb = (size_t)g * GSEG;
    for (int k = 0; k < 3; ++k) {
        int j0 = (tid + 1024 * k) * 4;
        const uint4 p4 = *(const uint4*)&im2_pay[gb + j0];
        const ushort4 e4 = *(const ushort4*)&im2_el[gb + j0];
        win2[e4.x] = p4.x; win2[e4.y] = p4.y; win2[e4.z] = p4.z; win2[e4.w] = p4.w;
    }
    __syncthreads();
    for (int j = tid; j < GSEG; j += 1024) dest[gb + j] = win2[j];
    for (int k = 0; k < GSEG / 1024; ++k) {
        int le = tid + 1024 * k;
        uint32_t b = (win2[le] >> 3) >> 11;
        uint32_t r = atomicAdd(&cntF[b], 1u);
        f1rank[gb + le] = (uint8_t)r;
    }
    __syncthreads();
    if (tid < FBK) runcntF[(size_t)tid * FG + g] = cntF[tid];
}

// ---------------- scans (parallel: one block per row, LDS block-scan) ----------------
__global__ __launch_bounds__(256) void scanF_kernel(const uint32_t* __restrict__ runcntF,
                                                    uint32_t* __restrict__ f1base) {
    __shared__ uint32_t sc[512];
    const int tid = threadIdx.x, b = blockIdx.x;     // grid FBK
    uint32_t c0 = runcntF[(size_t)b * FG + tid];
    uint32_t c1 = runcntF[(size_t)b * FG + tid + 256];
    sc[tid] = c0; sc[tid + 256] = c1;
    __syncthreads();
    for (int d = 1; d < 512; d <<= 1) {
        uint32_t a0 = (tid >= d) ? sc[tid - d] : 0u;
        uint32_t a1 = sc[tid + 256 - d];
        __syncthreads();
        sc[tid] += a0; sc[tid + 256] += a1;
        __syncthreads();
    }
    uint32_t base = (uint32_t)b * CSEG;
    f1base[(size_t)tid * FBK + b] = base + sc[tid] - c0;
    f1base[(size_t)(tid + 256) * FBK + b] = base + sc[tid + 256] - c1;
}

__global__ __launch_bounds__(256) void scanB_kernel(const uint32_t* __restrict__ runcntB,
                                                    uint32_t* __restrict__ b1base) {
    __shared__ uint32_t sc[512];
    const int tid = threadIdx.x, bB = blockIdx.x;    // grid VBK=512
    uint32_t c0 = runcntB[(size_t)bB * FBK + tid];
    uint32_t c1 = runcntB[(size_t)bB * FBK + tid + 256];
    sc[tid] = c0; sc[tid + 256] = c1;
    __syncthreads();
    for (int d = 1; d < 512; d <<= 1) {
        uint32_t a0 = (tid >= d) ? sc[tid - d] : 0u;
        uint32_t a1 = sc[tid + 256 - d];
        __syncthreads();
        sc[tid] += a0; sc[tid + 256] += a1;
        __syncthreads();
    }
    uint32_t base = (uint32_t)bB * VSEG;
    b1base[(size_t)tid * VBK + bB] = base + sc[tid] - c0;
    b1base[(size_t)(tid + 256) * VBK + bB] = base + sc[tid + 256] - c1;
}

// ---------------- fb: forward sorted tables; 1024 threads ----------------
// lvF packs (lv<<2)|slot so var can compute per-edge v2c at scatter time.
__global__ __launch_bounds__(1024) void fb_kernel(const uint32_t* __restrict__ dest,
                                                  const uint8_t* __restrict__ f1rank,
                                                  const uint32_t* __restrict__ runcntF,
                                                  const uint32_t* __restrict__ f1base,
                                                  uint32_t* __restrict__ goffF,
                                                  uint16_t* __restrict__ f2pos,
                                                  uint16_t* __restrict__ bidxF,
                                                  uint16_t* __restrict__ lvF) {
    __shared__ uint32_t flb[FBK];        // 2 KB
    __shared__ uint32_t rowf[FBK];       // 2 KB
    __shared__ uint32_t sortv[GSEG];     // 48 KB
    const int tid = threadIdx.x, g = blockIdx.x;
    uint32_t c0 = 0;
    if (tid < FBK) {
        c0 = runcntF[(size_t)tid * FG + g];
        flb[tid] = c0;
        rowf[tid] = f1base[(size_t)g * FBK + tid];
    }
    __syncthreads();
    for (int d = 1; d < FBK; d <<= 1) {
        uint32_t a0 = 0;
        if (tid < FBK) a0 = (tid >= d) ? flb[tid - d] : 0u;
        __syncthreads();
        if (tid < FBK) flb[tid] += a0;
        __syncthreads();
    }
    if (tid < FBK) flb[tid] -= c0;
    __syncthreads();
    if (tid < FBK) goffF[(size_t)g * FBK + tid] = rowf[tid] - flb[tid];
    const size_t gb = (size_t)g * GSEG;
    // round 1: f2pos + bidxF
    for (int k = 0; k < GSEG / 1024; ++k) {
        int le = tid + 1024 * k;
        uint32_t d = dest[gb + le];
        uint32_t r = f1rank[gb + le];
        uint32_t c = d >> 3;
        uint32_t b = c >> 11;
        uint32_t pl = c * 6u + (d & 7u) - b * 12288u;
        sortv[flb[b] + r] = (b << 14) | pl;
    }
    __syncthreads();
    for (int k = 0; k < GSEG / 1024; ++k) {
        int j = tid + 1024 * k;
        uint32_t v = sortv[j];
        uint32_t b = v >> 14;
        f2pos[rowf[b] - flb[b] + j] = (uint16_t)(v & 16383u);
        bidxF[gb + j] = (uint16_t)b;
    }
    __syncthreads();
    // round 2: lvF = (lv<<2)|slot
    for (int k = 0; k < GSEG / 1024; ++k) {
        int le = tid + 1024 * k;
        uint32_t d = dest[gb + le];
        uint32_t r = f1rank[gb + le];
        uint32_t b = (d >> 3) >> 11;
        uint32_t lv = (uint32_t)(le / 3);
        uint32_t sl = (uint32_t)le - 3u * lv;
        sortv[flb[b] + r] = (lv << 2) | sl;
    }
    __syncthreads();
    for (int k = 0; k < GSEG / 1024; ++k) {
        int j = tid + 1024 * k;
        lvF[gb + j] = (uint16_t)sortv[j];
    }
}

// ---------------- bb: backward sorted tables; 1024 threads ----------------
// Segment sorted by var-block ascending -> bidxB stores bB&255; jsplit = #entries with bB<256.
__global__ __launch_bounds__(1024) void bb_kernel(const uint32_t* __restrict__ chk_edges,
                                                  const uint8_t* __restrict__ b1rank,
                                                  const uint32_t* __restrict__ runcntB,
                                                  const uint32_t* __restrict__ b1base,
                                                  uint32_t* __restrict__ goffB,
                                                  uint32_t* __restrict__ jsplit,
                                                  uint16_t* __restrict__ b2pos,
                                                  uint8_t* __restrict__ bidxB,
                                                  uint16_t* __restrict__ lposB) {
    __shared__ uint32_t blb[VBK];        // 2 KB
    __shared__ uint32_t rowb[VBK];       // 2 KB
    __shared__ uint32_t sortv[CSEG];     // 48 KB
    const int tid = threadIdx.x, blk = blockIdx.x;
    uint32_t c0 = 0;
    if (tid < VBK) {
        c0 = runcntB[(size_t)tid * FBK + blk];
        blb[tid] = c0;
        rowb[tid] = b1base[(size_t)blk * VBK + tid];
    }
    __syncthreads();
    for (int d = 1; d < VBK; d <<= 1) {
        uint32_t a0 = 0;
        if (tid < VBK) a0 = (tid >= d) ? blb[tid - d] : 0u;
        __syncthreads();
        if (tid < VBK) blb[tid] += a0;
        __syncthreads();
    }
    if (tid < VBK) blb[tid] -= c0;
    __syncthreads();
    if (tid < VBK) goffB[(size_t)blk * VBK + tid] = rowb[tid] - blb[tid];
    if (tid == 0) jsplit[blk] = blb[256];          // entries with bB<256
    const size_t cb = (size_t)blk * CSEG;
    // round 1: b2pos + bidxB (low byte of bB)
    for (int k = 0; k < CSEG / 1024; ++k) {
        int lp = tid + 1024 * k;
        uint32_t e = chk_edges[cb + lp];
        uint32_t r = b1rank[cb + lp];
        uint32_t bB = (e / 3u) >> 12;
        uint32_t elocal = e - bB * VSEG;
        sortv[blb[bB] + r] = (bB << 14) | elocal;
    }
    __syncthreads();
    for (int k = 0; k < CSEG / 1024; ++k) {
        int j = tid + 1024 * k;
        uint32_t v = sortv[j];
        b2pos[(size_t)rowb[v >> 14] - blb[v >> 14] + j] = (uint16_t)(v & 16383u);
        bidxB[cb + j] = (uint8_t)(v >> 14);        // bB & 255 (position recovers bit 8)
    }
    __syncthreads();
    // round 2: lposB
    for (int k = 0; k < CSEG / 1024; ++k) {
        int lp = tid + 1024 * k;
        uint32_t e = chk_edges[cb + lp];
        uint32_t r = b1rank[cb + lp];
        uint32_t bB = (e / 3u) >> 12;
        sortv[blb[bB] + r] = (uint32_t)lp;
    }
    __syncthreads();
    for (int k = 0; k < CSEG / 1024; ++k) {
        int j = tid + 1024 * k;
        lposB[cb + j] = (uint16_t)sortv[j];
    }
}

// ---------------- per-iteration check kernel; 1024 threads ----------------
__global__ __launch_bounds__(1024) void check_kernel(const float* __restrict__ finterm,
                                                     const uint16_t* __restrict__ f2pos,
                                                     const uint16_t* __restrict__ lposB,
                                                     const uint8_t* __restrict__ bidxB,
                                                     const uint32_t* __restrict__ goffB,
                                                     const uint32_t* __restrict__ jsplit,
                                                     uint8_t* __restrict__ binterm,
                                                     const float* __restrict__ beta,
                                                     const float* __restrict__ thresholds,
                                                     int t) {
    __shared__ __align__(16) float fwin[CSEG];   // 48 KB; front 8 KB reused as ewin
    __shared__ uint32_t grow[VBK];               // 2 KB
    uint32_t* ewin = (uint32_t*)fwin;
    const int tid = threadIdx.x, blk = blockIdx.x;
    if (tid < VBK) grow[tid] = goffB[(size_t)blk * VBK + tid];
    const uint32_t js = jsplit[blk];
    const size_t cb = (size_t)blk * CSEG;
    for (int k = 0; k < 3; ++k) {
        int j0 = (tid + 1024 * k) * 4;
        const float4 f4 = *(const float4*)&finterm[cb + j0];
        const ushort4 p4 = *(const ushort4*)&f2pos[cb + j0];
        fwin[p4.x] = f4.x; fwin[p4.y] = f4.y; fwin[p4.z] = f4.z; fwin[p4.w] = f4.w;
    }
    __syncthreads();

    const float b = beta[t];
    const float* thc = thresholds + t * 8;
    const float th1 = thc[1], th2 = thc[2], th3 = thc[3], th4 = thc[4];
    const float th5 = thc[5], th6 = thc[6], th7 = thc[7];
    const uint32_t signb = (b < 0.0f) ? 1u : 0u;

    uint32_t wreg[2];
    for (int i = 0; i < 2; ++i) {
        int lc = tid + 1024 * i;
        float mags[6];
        uint32_t sgn[6];
        uint32_t parity = 0;
        uint64_t minkey = ~0ull;
#pragma unroll
        for (int j = 0; j < 6; ++j) {
            float x = fwin[lc * 6 + j];            // v2c directly
            uint32_t s = (x < 0.0f) ? 1u : 0u;
            parity ^= s;
            sgn[j] = s;
            float mg = fabsf(x);
            mags[j] = mg;
            uint64_t key = (((uint64_t)__float_as_uint(mg)) << 3) | (uint32_t)j;
            minkey = (key < minkey) ? key : minkey;
        }
        float min1 = __uint_as_float((uint32_t)(minkey >> 3));
        uint32_t fs = (uint32_t)(minkey & 7u);
        float min2 = INFINITY;
#pragma unroll
        for (int j = 0; j < 6; ++j) {
            if ((uint32_t)j != fs) min2 = fminf(min2, mags[j]);
        }
        float m1 = fabsf(b * min1);
        float m2 = fabsf(b * min2);
        uint32_t q1 = (uint32_t)(m1 >= th1) + (uint32_t)(m1 >= th2) + (uint32_t)(m1 >= th3)
                    + (uint32_t)(m1 >= th4) + (uint32_t)(m1 >= th5) + (uint32_t)(m1 >= th6)
                    + (uint32_t)(m1 >= th7);
        uint32_t q2 = (uint32_t)(m2 >= th1) + (uint32_t)(m2 >= th2) + (uint32_t)(m2 >= th3)
                    + (uint32_t)(m2 >= th4) + (uint32_t)(m2 >= th5) + (uint32_t)(m2 >= th6)
                    + (uint32_t)(m2 >= th7);
        uint32_t w = 0;
#pragma unroll
        for (int j = 0; j < 6; ++j) {
            uint32_t neg = signb ^ parity ^ sgn[j];
            uint32_t q = ((uint32_t)j == fs) ? q2 : q1;
            w |= ((neg << 3) | q) << (4 * j);
        }
        wreg[i] = w;
    }
    __syncthreads();                 // fwin reads done; safe to alias ewin
    for (int i = 0; i < 2; ++i) {
        int lc = tid + 1024 * i;
        ewin[lc] = wreg[i];
    }
    __syncthreads();
    for (int k = 0; k < 3; ++k) {
        int j0 = (tid + 1024 * k) * 4;
        const ushort4 lp4 = *(const ushort4*)&lposB[cb + j0];
        const uchar4 b4 = *(const uchar4*)&bidxB[cb + j0];
        uint32_t lp, word, bB;
        lp = lp4.x; word = ewin[lp / 6u];
        bB = (uint32_t)b4.x + (((uint32_t)(j0 + 0) >= js) ? 256u : 0u);
        binterm[grow[bB] + j0 + 0] = (uint8_t)((word >> ((lp - 6u * (lp / 6u)) * 4u)) & 15u);
        lp = lp4.y; word = ewin[lp / 6u];
        bB = (uint32_t)b4.y + (((uint32_t)(j0 + 1) >= js) ? 256u : 0u);
        binterm[grow[bB] + j0 + 1] = (uint8_t)((word >> ((lp - 6u * (lp / 6u)) * 4u)) & 15u);
        lp = lp4.z; word = ewin[lp / 6u];
        bB = (uint32_t)b4.z + (((uint32_t)(j0 + 2) >= js) ? 256u : 0u);
        binterm[grow[bB] + j0 + 2] = (uint8_t)((word >> ((lp - 6u * (lp / 6u)) * 4u)) & 15u);
        lp = lp4.w; word = ewin[lp / 6u];
        bB = (uint32_t)b4.w + (((uint32_t)(j0 + 3) >= js) ? 256u : 0u);
        binterm[grow[bB] + j0 + 3] = (uint8_t)((word >> ((lp - 6u * (lp / 6u)) * 4u)) & 15u);
    }
}

// ---------------- per-iteration variable kernel; grid 512 x 1024 ----------------
// 4096 vars/block; forward group g == vblk. LDS ~30 KB -> 2 blocks/CU if VGPR<=64.
// Scatter writes per-edge v2c = alpha[t]*(post - c2v_edge) — bit-identical chain.
__global__ __launch_bounds__(1024) void var_kernel(const float* __restrict__ llr,
                                                   const uint8_t* __restrict__ binterm,
                                                   const uint16_t* __restrict__ b2pos,
                                                   const uint16_t* __restrict__ lvF,
                                                   const uint16_t* __restrict__ bidxF,
                                                   const uint32_t* __restrict__ goffF,
                                                   float* __restrict__ finterm,
                                                   const float* __restrict__ thresholds,
                                                   const float* __restrict__ alpha,
                                                   int t, int mode,
                                                   float* __restrict__ out) {
    __shared__ uint8_t nwin[VSEG];       // 12 KB
    __shared__ float pwin[4096];         // 16 KB
    __shared__ uint32_t growF[FBK];      // 2 KB
    __shared__ float tl[8];
    const int tid = threadIdx.x, vblk = blockIdx.x;   // grid VBK=512
    if (tid < 8) tl[tid] = thresholds[t * 8 + tid];
    if (mode != 1) {
        const size_t vb = (size_t)vblk * VSEG;
        for (int k = 0; k < 3; ++k) {
            int i0 = (tid + 1024 * k) * 4;
            const uchar4 n4 = *(const uchar4*)&binterm[vb + i0];
            const ushort4 p4 = *(const ushort4*)&b2pos[vb + i0];
            nwin[p4.x] = n4.x; nwin[p4.y] = n4.y; nwin[p4.z] = n4.z; nwin[p4.w] = n4.w;
        }
    }
    __syncthreads();
    const float a = (mode == 1) ? 1.0f : alpha[t];
    for (int i = 0; i < 4; ++i) {
        int lv = tid + 1024 * i;
        int v = vblk * 4096 + lv;
        float post;
        if (mode == 1) {
            post = llr[v];
        } else {
            uint32_t n0 = nwin[3 * lv], n1 = nwin[3 * lv + 1], n2 = nwin[3 * lv + 2];
            float c0 = (n0 & 8u) ? -tl[n0 & 7u] : tl[n0 & 7u];
            float c1 = (n1 & 8u) ? -tl[n1 & 7u] : tl[n1 & 7u];
            float c2 = (n2 & 8u) ? -tl[n2 & 7u] : tl[n2 & 7u];
            post = llr[v] + ((c0 + c1) + c2);      // reference summation order
        }
        pwin[lv] = post;
        if (mode == 2) {
            out[v] = (post < 0.0f) ? 1.0f : 0.0f;
            out[NV + v] = post;
            if (v == 0) out[2 * NV] = 10.0f;
        }
    }
    if (mode == 2) return;                         // uniform across block
    if (tid < FBK) growF[tid] = goffF[(size_t)vblk * FBK + tid];
    __syncthreads();                               // pwin + growF ready
    const size_t gb = (size_t)vblk * GSEG;
    for (int k = 0; k < 3; ++k) {
        int j0 = (tid + 1024 * k) * 4;
        const ushort4 lv4 = *(const ushort4*)&lvF[gb + j0];
        const ushort4 b4 = *(const ushort4*)&bidxF[gb + j0];
        float v0, v1, v2, v3;
        if (mode == 1) {
            v0 = pwin[lv4.x >> 2]; v1 = pwin[lv4.y >> 2];
            v2 = pwin[lv4.z >> 2]; v3 = pwin[lv4.w >> 2];
        } else {
            uint32_t e, lvq, nib; float c;
            e = lv4.x; lvq = e >> 2; nib = nwin[3 * lvq + (e & 3u)];
            c = (nib & 8u) ? -tl[nib & 7u] : tl[nib & 7u];
            v0 = a * (pwin[lvq] - c);
            e = lv4.y; lvq = e >> 2; nib = nwin[3 * lvq + (e & 3u)];
            c = (nib & 8u) ? -tl[nib & 7u] : tl[nib & 7u];
            v1 = a * (pwin[lvq] - c);
            e = lv4.z; lvq = e >> 2; nib = nwin[3 * lvq + (e & 3u)];
            c = (nib & 8u) ? -tl[nib & 7u] : tl[nib & 7u];
            v2 = a * (pwin[lvq] - c);
            e = lv4.w; lvq = e >> 2; nib = nwin[3 * lvq + (e & 3u)];
            c = (nib & 8u) ? -tl[nib & 7u] : tl[nib & 7u];
            v3 = a * (pwin[lvq] - c);
        }
        finterm[growF[b4.x] + j0 + 0] = v0;
        finterm[growF[b4.y] + j0 + 1] = v1;
        finterm[growF[b4.z] + j0 + 2] = v2;
        finterm[growF[b4.w] + j0 + 3] = v3;
    }
}

extern "C" void kernel_launch(void* const* d_in, const int* in_sizes, int n_in,
                              void* d_out, int out_size, void* d_ws, size_t ws_size,
                              hipStream_t stream) {
    const float* llr        = (const float*)d_in[0];
    const int*   var_idx    = (const int*)d_in[1];   (void)var_idx;   // implicit e/3
    const int*   chk_idx    = (const int*)d_in[2];
    const float* beta       = (const float*)d_in[3];
    const float* alpha      = (const float*)d_in[4];
    const float* thresholds = (const float*)d_in[5];
    float* out = (float*)d_out;

    // workspace layout (~212 MB; im2 aliases im1 — im1 dead after place1)
    char* wsb = (char*)d_ws;
    float*    finterm   = (float*)(wsb + 0);                  // 25165824
    uint16_t* f2pos     = (uint16_t*)(wsb + 25165824);        // 12582912
    uint16_t* lvF       = (uint16_t*)(wsb + 37748736);        // 12582912
    uint16_t* bidxF     = (uint16_t*)(wsb + 50331648);        // 12582912
    uint16_t* lposB     = (uint16_t*)(wsb + 62914560);        // 12582912
    uint16_t* b2pos     = (uint16_t*)(wsb + 75497472);        // 12582912
    uint8_t*  bidxB     = (uint8_t*)(wsb + 88080384);         // 6291456
    uint8_t*  binterm   = (uint8_t*)(wsb + 94371840);         // 6291456
    uint32_t* chk_edges = (uint32_t*)(wsb + 104857600);       // 25165824
    uint32_t* dest      = (uint32_t*)(wsb + 130023424);       // 25165824
    uint32_t* im1_e     = (uint32_t*)(wsb + 155189248);       // 25165824
    uint16_t* im1_c     = (uint16_t*)(wsb + 180355072);       // 12582912
    uint32_t* im2_pay   = im1_e;                              // alias (im1 dead)
    uint16_t* im2_el    = im1_c;                              // alias
    uint8_t*  f1rank    = (uint8_t*)(wsb + 192937984);        // 6291456
    uint8_t*  b1rank    = (uint8_t*)(wsb + 199229440);        // 6291456
    uint32_t* runcntF   = (uint32_t*)(wsb + 205520896);       // 1048576
    uint32_t* f1base    = (uint32_t*)(wsb + 206569472);       // 1048576
    uint32_t* runcntB   = (uint32_t*)(wsb + 207618048);       // 1048576 (VBK*FBK*4)
    uint32_t* b1base    = (uint32_t*)(wsb + 208666624);       // 1048576 (FBK*VBK*4)
    uint32_t* goffF     = (uint32_t*)(wsb + 209715200);       // 1048576
    uint32_t* goffB     = (uint32_t*)(wsb + 210763776);       // 1048576 (FBK*VBK*4)
    uint32_t* jsplit    = (uint32_t*)(wsb + 211812352);       // 2048
    uint32_t* gcur      = (uint32_t*)(wsb + 211814400);       // 4096
    uint32_t* gcurA     = gcur;
    uint32_t* gcurB     = gcur + 512;

    initcur_kernel<<<2, 512, 0, stream>>>(gcur);
    bin1_kernel<<<NBLK, 512, 0, stream>>>(chk_idx, gcurA, im1_e, im1_c);
    place1_kernel<<<FBK, 1024, 0, stream>>>(im1_e, im1_c, chk_edges, b1rank, runcntB);
    bin2_kernel<<<NBLK, 512, 0, stream>>>(chk_edges, gcurB, im2_pay, im2_el);
    place2_kernel<<<FG, 1024, 0, stream>>>(im2_pay, im2_el, dest, f1rank, runcntF);
    scanF_kernel<<<FBK, 256, 0, stream>>>(runcntF, f1base);
    fb_kernel<<<FG, 1024, 0, stream>>>(dest, f1rank, runcntF, f1base, goffF, f2pos, bidxF, lvF);
    scanB_kernel<<<VBK, 256, 0, stream>>>(runcntB, b1base);
    bb_kernel<<<FBK, 1024, 0, stream>>>(chk_edges, b1rank, runcntB, b1base, goffB, jsplit,
                                        b2pos, bidxB, lposB);
    // seed: finterm <- llr (v2c_0) via forward permute (mode 1)
    var_kernel<<<VBK, 1024, 0, stream>>>(llr, binterm, b2pos, lvF, bidxF, goffF,
                                         finterm, thresholds, alpha, 0, 1, out);

    for (int t = 0; t < TT; ++t) {
        check_kernel<<<FBK, 1024, 0, stream>>>(finterm, f2pos, lposB, bidxB, goffB, jsplit,
                                               binterm, beta, thresholds, t);
        var_kernel<<<VBK, 1024, 0, stream>>>(llr, binterm, b2pos, lvF, bidxF, goffF,
                                             finterm, thresholds, alpha, t,
                                             (t == TT - 1) ? 2 : 0, out);
    }
}

// Round 11
// 618.206 us; speedup vs baseline: 1.0392x; 1.0323x over previous
//
#include <hip/hip_runtime.h>
#include <stdint.h>

#define NV 2097152
#define MC 1048576
#define EE 6291456
#define TT 10

#define CHUNK 8192
#define NBLK 768        // EE / CHUNK
#define FBK 512         // check blocks: 2048 checks = 12288 positions each
#define CPB 2048
#define CSEG 12288
#define FG 512          // forward groups: 4096 vars = 12288 edges each
#define GSEG 12288
#define VBK 256         // var blocks: 8192 vars = 24576 edge-nibbles each
#define VSEG 24576

// ---------------- cursor init: gcur[b] = b*12288 for both bin passes ----------------
__global__ __launch_bounds__(512) void initcur_kernel(uint32_t* __restrict__ gcur) {
    int i = blockIdx.x * 512 + threadIdx.x;     // grid 2x512 -> 1024
    gcur[i] = (uint32_t)(i & 511) * 12288u;
}

// ---------------- bin1: bucket edges by check-block, dest-sorted; 512 threads ----------------
// grid 768 = 3/CU fully co-resident (1536 thr/CU)
__global__ __launch_bounds__(512) void bin1_kernel(const int* __restrict__ chk_idx,
                                                   uint32_t* __restrict__ gcurA,
                                                   uint32_t* __restrict__ im1_e,
                                                   uint16_t* __restrict__ im1_c) {
    __shared__ uint32_t cnt0[512];     // 2 KB
    __shared__ uint32_t aux[512];      // 2 KB: counts -> scan -> adj
    __shared__ uint32_t sA[CHUNK];     // 32 KB: (b<<23)|e
    __shared__ uint16_t sB[CHUNK];     // 16 KB: clow
    const int tid = threadIdx.x;
    const int rep = tid >> 8;
    const int base = blockIdx.x * CHUNK;
    cnt0[tid] = 0; aux[tid] = 0;
    __syncthreads();
    int4 cc4[4];
#pragma unroll
    for (int k = 0; k < 4; ++k) cc4[k] = ((const int4*)chk_idx)[(base >> 2) + tid + 512 * k];
    uint32_t br[16];                   // (b<<13)|rank
#pragma unroll
    for (int k = 0; k < 4; ++k) {
        int cv[4] = {cc4[k].x, cc4[k].y, cc4[k].z, cc4[k].w};
#pragma unroll
        for (int ii = 0; ii < 4; ++ii) {
            uint32_t b = (uint32_t)cv[ii] >> 11;
            uint32_t r = atomicAdd(rep ? &aux[b] : &cnt0[b], 1u);
            br[k * 4 + ii] = (b << 13) | r;
        }
    }
    __syncthreads();
    const uint32_t s0 = cnt0[tid] + aux[tid];
    aux[tid] = s0;
    __syncthreads();
    for (int d = 1; d < 512; d <<= 1) {
        uint32_t a0 = (tid >= d) ? aux[tid - d] : 0u;
        __syncthreads();
        aux[tid] += a0;
        __syncthreads();
    }
    const uint32_t excl0 = aux[tid] - s0;
    aux[tid] = excl0;
    const uint32_t gb0 = atomicAdd(&gcurA[tid], s0);
    __syncthreads();
    // pass B: scatter into LDS staging at sorted slot
#pragma unroll
    for (int k = 0; k < 4; ++k) {
        int cv[4] = {cc4[k].x, cc4[k].y, cc4[k].z, cc4[k].w};
#pragma unroll
        for (int ii = 0; ii < 4; ++ii) {
            uint32_t v = br[k * 4 + ii];
            uint32_t b = v >> 13;
            uint32_t r = v & 8191u;
            uint32_t j = aux[b] + (rep ? cnt0[b] : 0u) + r;
            uint32_t e = (uint32_t)(base + (tid + 512 * k) * 4 + ii);
            sA[j] = (b << 23) | e;
            sB[j] = (uint16_t)((uint32_t)cv[ii] & 2047u);
        }
    }
    __syncthreads();
    aux[tid] = gb0 - excl0;            // adj
    __syncthreads();
    // pass C: coalesced run writes, payload from LDS
#pragma unroll 8
    for (int k = 0; k < 16; ++k) {
        int j = tid + 512 * k;
        uint32_t v = sA[j];
        uint32_t b = v >> 23;
        uint32_t addr = aux[b] + (uint32_t)j;
        im1_e[addr] = v & 0x7FFFFFu;
        im1_c[addr] = sB[j];
    }
}

// ---------------- place1 + ba fused; 1024 threads (grid 512 -> 2 blk/CU = 2048 thr) ----------------
__global__ __launch_bounds__(1024) void place1_kernel(const uint32_t* __restrict__ im1_e,
                                                      const uint16_t* __restrict__ im1_c,
                                                      uint32_t* __restrict__ chk_edges,
                                                      uint8_t* __restrict__ b1rank,
                                                      uint32_t* __restrict__ runcntB) {
    __shared__ uint32_t win[CSEG];       // 48 KB
    __shared__ uint32_t ccnt[CPB / 2];   // 4 KB packed
    __shared__ uint32_t cntB[VBK];       // 1 KB
    const int tid = threadIdx.x, blk = blockIdx.x;
    ccnt[tid] = 0;                       // CPB/2 == 1024
    if (tid < VBK) cntB[tid] = 0;
    __syncthreads();
    const size_t cb = (size_t)blk * CSEG;
    for (int k = 0; k < 3; ++k) {
        int j0 = (tid + 1024 * k) * 4;
        const uint4 e4 = *(const uint4*)&im1_e[cb + j0];
        const ushort4 c4 = *(const ushort4*)&im1_c[cb + j0];
        uint32_t c, old, s;
        c = c4.x; old = atomicAdd(&ccnt[c >> 1], 1u << ((c & 1) * 16));
        s = (old >> ((c & 1) * 16)) & 0xFFFFu; win[c * 6 + s] = e4.x;
        c = c4.y; old = atomicAdd(&ccnt[c >> 1], 1u << ((c & 1) * 16));
        s = (old >> ((c & 1) * 16)) & 0xFFFFu; win[c * 6 + s] = e4.y;
        c = c4.z; old = atomicAdd(&ccnt[c >> 1], 1u << ((c & 1) * 16));
        s = (old >> ((c & 1) * 16)) & 0xFFFFu; win[c * 6 + s] = e4.z;
        c = c4.w; old = atomicAdd(&ccnt[c >> 1], 1u << ((c & 1) * 16));
        s = (old >> ((c & 1) * 16)) & 0xFFFFu; win[c * 6 + s] = e4.w;
    }
    __syncthreads();
    for (int j = tid; j < CSEG; j += 1024) chk_edges[cb + j] = win[j];
    for (int k = 0; k < CSEG / 1024; ++k) {
        int lp = tid + 1024 * k;
        uint32_t e = win[lp];
        uint32_t bB = (e / 3u) >> 13;
        uint32_t r = atomicAdd(&cntB[bB], 1u);
        b1rank[cb + lp] = (uint8_t)r;
    }
    __syncthreads();
    if (tid < VBK) runcntB[(size_t)tid * FBK + blk] = cntB[tid];
}

// ---------------- bin2: bucket (position -> edge) by var-group; 512 threads ----------------
__global__ __launch_bounds__(512) void bin2_kernel(const uint32_t* __restrict__ chk_edges,
                                                   uint32_t* __restrict__ gcurB,
                                                   uint32_t* __restrict__ im2_pay,
                                                   uint16_t* __restrict__ im2_el) {
    __shared__ uint32_t cnt0[512];
    __shared__ uint32_t aux[512];
    __shared__ uint32_t sA[CHUNK];     // (vb<<13)|pos_local
    __shared__ uint16_t sB[CHUNK];     // elow
    const int tid = threadIdx.x;
    const int rep = tid >> 8;
    const int base = blockIdx.x * CHUNK;
    cnt0[tid] = 0; aux[tid] = 0;
    __syncthreads();
    uint4 ee4[4];
#pragma unroll
    for (int k = 0; k < 4; ++k) ee4[k] = ((const uint4*)chk_edges)[(base >> 2) + tid + 512 * k];
    uint32_t br[16];
#pragma unroll
    for (int k = 0; k < 4; ++k) {
        uint32_t ev[4] = {ee4[k].x, ee4[k].y, ee4[k].z, ee4[k].w};
#pragma unroll
        for (int ii = 0; ii < 4; ++ii) {
            uint32_t vb = ev[ii] / 12288u;
            uint32_t r = atomicAdd(rep ? &aux[vb] : &cnt0[vb], 1u);
            br[k * 4 + ii] = (vb << 13) | r;
        }
    }
    __syncthreads();
    const uint32_t s0 = cnt0[tid] + aux[tid];
    aux[tid] = s0;
    __syncthreads();
    for (int d = 1; d < 512; d <<= 1) {
        uint32_t a0 = (tid >= d) ? aux[tid - d] : 0u;
        __syncthreads();
        aux[tid] += a0;
        __syncthreads();
    }
    const uint32_t excl0 = aux[tid] - s0;
    aux[tid] = excl0;
    const uint32_t gb0 = atomicAdd(&gcurB[tid], s0);
    __syncthreads();
#pragma unroll
    for (int k = 0; k < 4; ++k) {
        uint32_t ev[4] = {ee4[k].x, ee4[k].y, ee4[k].z, ee4[k].w};
#pragma unroll
        for (int ii = 0; ii < 4; ++ii) {
            uint32_t v = br[k * 4 + ii];
            uint32_t vb = v >> 13;
            uint32_t r = v & 8191u;
            uint32_t j = aux[vb] + (rep ? cnt0[vb] : 0u) + r;
            uint32_t pl = (uint32_t)((tid + 512 * k) * 4 + ii);
            sA[j] = (vb << 13) | pl;
            sB[j] = (uint16_t)(ev[ii] - vb * 12288u);
        }
    }
    __syncthreads();
    aux[tid] = gb0 - excl0;            // adj
    __syncthreads();
#pragma unroll 8
    for (int k = 0; k < 16; ++k) {
        int j = tid + 512 * k;
        uint32_t v = sA[j];
        uint32_t vb = v >> 13;
        uint32_t pos = (uint32_t)base + (v & 8191u);
        uint32_t c = pos / 6u;
        uint32_t s = pos - c * 6u;
        uint32_t addr = aux[vb] + (uint32_t)j;
        im2_pay[addr] = (c << 3) | s;
        im2_el[addr] = sB[j];
    }
}

// ---------------- place2 + fa fused; 1024 threads ----------------
__global__ __launch_bounds__(1024) void place2_kernel(const uint32_t* __restrict__ im2_pay,
                                                      const uint16_t* __restrict__ im2_el,
                                                      uint32_t* __restrict__ dest,
                                                      uint8_t* __restrict__ f1rank,
                                                      uint32_t* __restrict__ runcntF) {
    __shared__ uint32_t win2[GSEG];      // 48 KB
    __shared__ uint32_t cntF[FBK];       // 2 KB
    const int tid = threadIdx.x, g = blockIdx.x;
    if (tid < FBK) cntF[tid] = 0;
    __syncthreads();
    const size_t gb = (size_t)g * GSEG;
    for (int k = 0; k < 3; ++k) {
        int j0 = (tid + 1024 * k) * 4;
        const uint4 p4 = *(const uint4*)&im2_pay[gb + j0];
        const ushort4 e4 = *(const ushort4*)&im2_el[gb + j0];
        win2[e4.x] = p4.x; win2[e4.y] = p4.y; win2[e4.z] = p4.z; win2[e4.w] = p4.w;
    }
    __syncthreads();
    for (int j = tid; j < GSEG; j += 1024) dest[gb + j] = win2[j];
    for (int k = 0; k < GSEG / 1024; ++k) {
        int le = tid + 1024 * k;
        uint32_t b = (win2[le] >> 3) >> 11;
        uint32_t r = atomicAdd(&cntF[b], 1u);
        f1rank[gb + le] = (uint8_t)r;
    }
    __syncthreads();
    if (tid < FBK) runcntF[(size_t)tid * FG + g] = cntF[tid];
}

// ---------------- scans (parallel: one block per row, LDS block-scan) ----------------
__global__ __launch_bounds__(256) void scanF_kernel(const uint32_t* __restrict__ runcntF,
                                                    uint32_t* __restrict__ f1base) {
    __shared__ uint32_t sc[512];
    const int tid = threadIdx.x, b = blockIdx.x;     // grid FBK
    uint32_t c0 = runcntF[(size_t)b * FG + tid];
    uint32_t c1 = runcntF[(size_t)b * FG + tid + 256];
    sc[tid] = c0; sc[tid + 256] = c1;
    __syncthreads();
    for (int d = 1; d < 512; d <<= 1) {
        uint32_t a0 = (tid >= d) ? sc[tid - d] : 0u;
        uint32_t a1 = sc[tid + 256 - d];
        __syncthreads();
        sc[tid] += a0; sc[tid + 256] += a1;
        __syncthreads();
    }
    uint32_t base = (uint32_t)b * CSEG;
    f1base[(size_t)tid * FBK + b] = base + sc[tid] - c0;
    f1base[(size_t)(tid + 256) * FBK + b] = base + sc[tid + 256] - c1;
}

__global__ __launch_bounds__(256) void scanB_kernel(const uint32_t* __restrict__ runcntB,
                                                    uint32_t* __restrict__ b1base) {
    __shared__ uint32_t sc[512];
    const int tid = threadIdx.x, bB = blockIdx.x;    // grid VBK
    uint32_t c0 = runcntB[(size_t)bB * FBK + tid];
    uint32_t c1 = runcntB[(size_t)bB * FBK + tid + 256];
    sc[tid] = c0; sc[tid + 256] = c1;
    __syncthreads();
    for (int d = 1; d < 512; d <<= 1) {
        uint32_t a0 = (tid >= d) ? sc[tid - d] : 0u;
        uint32_t a1 = sc[tid + 256 - d];
        __syncthreads();
        sc[tid] += a0; sc[tid + 256] += a1;
        __syncthreads();
    }
    uint32_t base = (uint32_t)bB * VSEG;
    b1base[(size_t)tid * VBK + bB] = base + sc[tid] - c0;
    b1base[(size_t)(tid + 256) * VBK + bB] = base + sc[tid + 256] - c1;
}

// ---------------- fb: forward sorted tables; 1024 threads ----------------
// lvF packs (lv<<2)|slot so var can compute per-edge v2c at scatter time.
__global__ __launch_bounds__(1024) void fb_kernel(const uint32_t* __restrict__ dest,
                                                  const uint8_t* __restrict__ f1rank,
                                                  const uint32_t* __restrict__ runcntF,
                                                  const uint32_t* __restrict__ f1base,
                                                  uint32_t* __restrict__ goffF,
                                                  uint16_t* __restrict__ f2pos,
                                                  uint16_t* __restrict__ bidxF,
                                                  uint16_t* __restrict__ lvF) {
    __shared__ uint32_t flb[FBK];        // 2 KB
    __shared__ uint32_t rowf[FBK];       // 2 KB
    __shared__ uint32_t sortv[GSEG];     // 48 KB
    const int tid = threadIdx.x, g = blockIdx.x;
    uint32_t c0 = 0;
    if (tid < FBK) {
        c0 = runcntF[(size_t)tid * FG + g];
        flb[tid] = c0;
        rowf[tid] = f1base[(size_t)g * FBK + tid];
    }
    __syncthreads();
    for (int d = 1; d < FBK; d <<= 1) {
        uint32_t a0 = 0;
        if (tid < FBK) a0 = (tid >= d) ? flb[tid - d] : 0u;
        __syncthreads();
        if (tid < FBK) flb[tid] += a0;
        __syncthreads();
    }
    if (tid < FBK) flb[tid] -= c0;
    __syncthreads();
    if (tid < FBK) goffF[(size_t)g * FBK + tid] = rowf[tid] - flb[tid];
    const size_t gb = (size_t)g * GSEG;
    // round 1: f2pos + bidxF
    for (int k = 0; k < GSEG / 1024; ++k) {
        int le = tid + 1024 * k;
        uint32_t d = dest[gb + le];
        uint32_t r = f1rank[gb + le];
        uint32_t c = d >> 3;
        uint32_t b = c >> 11;
        uint32_t pl = c * 6u + (d & 7u) - b * 12288u;
        sortv[flb[b] + r] = (b << 14) | pl;
    }
    __syncthreads();
    for (int k = 0; k < GSEG / 1024; ++k) {
        int j = tid + 1024 * k;
        uint32_t v = sortv[j];
        uint32_t b = v >> 14;
        f2pos[rowf[b] - flb[b] + j] = (uint16_t)(v & 16383u);
        bidxF[gb + j] = (uint16_t)b;
    }
    __syncthreads();
    // round 2: lvF = (lv<<2)|slot
    for (int k = 0; k < GSEG / 1024; ++k) {
        int le = tid + 1024 * k;
        uint32_t d = dest[gb + le];
        uint32_t r = f1rank[gb + le];
        uint32_t b = (d >> 3) >> 11;
        uint32_t lv = (uint32_t)(le / 3);
        uint32_t sl = (uint32_t)le - 3u * lv;
        sortv[flb[b] + r] = (lv << 2) | sl;
    }
    __syncthreads();
    for (int k = 0; k < GSEG / 1024; ++k) {
        int j = tid + 1024 * k;
        lvF[gb + j] = (uint16_t)sortv[j];
    }
}

// ---------------- bb: backward sorted tables; 1024 threads ----------------
__global__ __launch_bounds__(1024) void bb_kernel(const uint32_t* __restrict__ chk_edges,
                                                  const uint8_t* __restrict__ b1rank,
                                                  const uint32_t* __restrict__ runcntB,
                                                  const uint32_t* __restrict__ b1base,
                                                  uint32_t* __restrict__ goffB,
                                                  uint16_t* __restrict__ b2pos,
                                                  uint8_t* __restrict__ bidxB,
                                                  uint16_t* __restrict__ lposB) {
    __shared__ uint32_t blb[VBK];        // 1 KB
    __shared__ uint32_t rowb[VBK];       // 1 KB
    __shared__ uint32_t sortv[CSEG];     // 48 KB
    const int tid = threadIdx.x, blk = blockIdx.x;
    uint32_t c0 = 0;
    if (tid < VBK) {
        c0 = runcntB[(size_t)tid * FBK + blk];
        blb[tid] = c0;
        rowb[tid] = b1base[(size_t)blk * VBK + tid];
    }
    __syncthreads();
    for (int d = 1; d < VBK; d <<= 1) {
        uint32_t a0 = 0;
        if (tid < VBK) a0 = (tid >= d) ? blb[tid - d] : 0u;
        __syncthreads();
        if (tid < VBK) blb[tid] += a0;
        __syncthreads();
    }
    if (tid < VBK) blb[tid] -= c0;
    __syncthreads();
    if (tid < VBK) goffB[(size_t)blk * VBK + tid] = rowb[tid] - blb[tid];
    const size_t cb = (size_t)blk * CSEG;
    // round 1: b2pos + bidxB
    for (int k = 0; k < CSEG / 1024; ++k) {
        int lp = tid + 1024 * k;
        uint32_t e = chk_edges[cb + lp];
        uint32_t r = b1rank[cb + lp];
        uint32_t bB = (e / 3u) >> 13;
        uint32_t elocal = e - bB * VSEG;
        sortv[blb[bB] + r] = (bB << 15) | elocal;
    }
    __syncthreads();
    for (int k = 0; k < CSEG / 1024; ++k) {
        int j = tid + 1024 * k;
        uint32_t v = sortv[j];
        uint32_t bB = v >> 15;
        b2pos[rowb[bB] - blb[bB] + j] = (uint16_t)(v & 32767u);
        bidxB[cb + j] = (uint8_t)bB;
    }
    __syncthreads();
    // round 2: lposB
    for (int k = 0; k < CSEG / 1024; ++k) {
        int lp = tid + 1024 * k;
        uint32_t e = chk_edges[cb + lp];
        uint32_t r = b1rank[cb + lp];
        uint32_t bB = (e / 3u) >> 13;
        sortv[blb[bB] + r] = (uint32_t)lp;
    }
    __syncthreads();
    for (int k = 0; k < CSEG / 1024; ++k) {
        int j = tid + 1024 * k;
        lposB[cb + j] = (uint16_t)sortv[j];
    }
}

// ---------------- per-iteration check kernel; 1024 threads ----------------
__global__ __launch_bounds__(1024) void check_kernel(const float* __restrict__ finterm,
                                                     const uint16_t* __restrict__ f2pos,
                                                     const uint16_t* __restrict__ lposB,
                                                     const uint8_t* __restrict__ bidxB,
                                                     const uint32_t* __restrict__ goffB,
                                                     uint8_t* __restrict__ binterm,
                                                     const float* __restrict__ beta,
                                                     const float* __restrict__ thresholds,
                                                     int t) {
    __shared__ __align__(16) float fwin[CSEG];   // 48 KB; front 8 KB reused as ewin
    __shared__ uint32_t grow[VBK];               // 1 KB
    uint32_t* ewin = (uint32_t*)fwin;
    const int tid = threadIdx.x, blk = blockIdx.x;
    if (tid < VBK) grow[tid] = goffB[(size_t)blk * VBK + tid];
    const size_t cb = (size_t)blk * CSEG;
    for (int k = 0; k < 3; ++k) {
        int j0 = (tid + 1024 * k) * 4;
        const float4 f4 = *(const float4*)&finterm[cb + j0];
        const ushort4 p4 = *(const ushort4*)&f2pos[cb + j0];
        fwin[p4.x] = f4.x; fwin[p4.y] = f4.y; fwin[p4.z] = f4.z; fwin[p4.w] = f4.w;
    }
    __syncthreads();

    const float b = beta[t];
    const float* thc = thresholds + t * 8;
    const float th1 = thc[1], th2 = thc[2], th3 = thc[3], th4 = thc[4];
    const float th5 = thc[5], th6 = thc[6], th7 = thc[7];
    const uint32_t signb = (b < 0.0f) ? 1u : 0u;

    uint32_t wreg[2];
    for (int i = 0; i < 2; ++i) {
        int lc = tid + 1024 * i;
        float mags[6];
        uint32_t sgn[6];
        uint32_t parity = 0;
        uint64_t minkey = ~0ull;
#pragma unroll
        for (int j = 0; j < 6; ++j) {
            float x = fwin[lc * 6 + j];            // v2c directly
            uint32_t s = (x < 0.0f) ? 1u : 0u;
            parity ^= s;
            sgn[j] = s;
            float mg = fabsf(x);
            mags[j] = mg;
            uint64_t key = (((uint64_t)__float_as_uint(mg)) << 3) | (uint32_t)j;
            minkey = (key < minkey) ? key : minkey;
        }
        float min1 = __uint_as_float((uint32_t)(minkey >> 3));
        uint32_t fs = (uint32_t)(minkey & 7u);
        float min2 = INFINITY;
#pragma unroll
        for (int j = 0; j < 6; ++j) {
            if ((uint32_t)j != fs) min2 = fminf(min2, mags[j]);
        }
        float m1 = fabsf(b * min1);
        float m2 = fabsf(b * min2);
        uint32_t q1 = (uint32_t)(m1 >= th1) + (uint32_t)(m1 >= th2) + (uint32_t)(m1 >= th3)
                    + (uint32_t)(m1 >= th4) + (uint32_t)(m1 >= th5) + (uint32_t)(m1 >= th6)
                    + (uint32_t)(m1 >= th7);
        uint32_t q2 = (uint32_t)(m2 >= th1) + (uint32_t)(m2 >= th2) + (uint32_t)(m2 >= th3)
                    + (uint32_t)(m2 >= th4) + (uint32_t)(m2 >= th5) + (uint32_t)(m2 >= th6)
                    + (uint32_t)(m2 >= th7);
        uint32_t w = 0;
#pragma unroll
        for (int j = 0; j < 6; ++j) {
            uint32_t neg = signb ^ parity ^ sgn[j];
            uint32_t q = ((uint32_t)j == fs) ? q2 : q1;
            w |= ((neg << 3) | q) << (4 * j);
        }
        wreg[i] = w;
    }
    __syncthreads();                 // fwin reads done; safe to alias ewin
    for (int i = 0; i < 2; ++i) {
        int lc = tid + 1024 * i;
        ewin[lc] = wreg[i];
    }
    __syncthreads();
    for (int k = 0; k < 3; ++k) {
        int j0 = (tid + 1024 * k) * 4;
        const ushort4 lp4 = *(const ushort4*)&lposB[cb + j0];
        const uchar4 b4 = *(const uchar4*)&bidxB[cb + j0];
        uint32_t lp, word;
        lp = lp4.x; word = ewin[lp / 6u];
        binterm[grow[b4.x] + j0 + 0] = (uint8_t)((word >> ((lp - 6u * (lp / 6u)) * 4u)) & 15u);
        lp = lp4.y; word = ewin[lp / 6u];
        binterm[grow[b4.y] + j0 + 1] = (uint8_t)((word >> ((lp - 6u * (lp / 6u)) * 4u)) & 15u);
        lp = lp4.z; word = ewin[lp / 6u];
        binterm[grow[b4.z] + j0 + 2] = (uint8_t)((word >> ((lp - 6u * (lp / 6u)) * 4u)) & 15u);
        lp = lp4.w; word = ewin[lp / 6u];
        binterm[grow[b4.w] + j0 + 3] = (uint8_t)((word >> ((lp - 6u * (lp / 6u)) * 4u)) & 15u);
    }
}

// ---------------- per-iteration variable kernel; 1024 threads ----------------
// Scatter writes per-edge v2c = alpha[t]*(post - c2v_edge) — bit-identical to reference chain.
__global__ __launch_bounds__(1024) void var_kernel(const float* __restrict__ llr,
                                                   const uint8_t* __restrict__ binterm,
                                                   const uint16_t* __restrict__ b2pos,
                                                   const uint16_t* __restrict__ lvF,
                                                   const uint16_t* __restrict__ bidxF,
                                                   const uint32_t* __restrict__ goffF,
                                                   float* __restrict__ finterm,
                                                   const float* __restrict__ thresholds,
                                                   const float* __restrict__ alpha,
                                                   int t, int mode,
                                                   float* __restrict__ out) {
    __shared__ uint8_t nwin[VSEG];       // 24 KB
    __shared__ float pwin[4096];         // 16 KB (one half)
    __shared__ uint32_t growF[FBK];      // 2 KB
    __shared__ float tl[8];
    const int tid = threadIdx.x, vblk = blockIdx.x;
    if (tid < 8) tl[tid] = thresholds[t * 8 + tid];
    if (mode != 1) {
        const size_t vb = (size_t)vblk * VSEG;
        for (int k = 0; k < 6; ++k) {
            int i0 = (tid + 1024 * k) * 4;
            const uchar4 n4 = *(const uchar4*)&binterm[vb + i0];
            const ushort4 p4 = *(const ushort4*)&b2pos[vb + i0];
            nwin[p4.x] = n4.x; nwin[p4.y] = n4.y; nwin[p4.z] = n4.z; nwin[p4.w] = n4.w;
        }
    }
    __syncthreads();
    const float a = (mode == 1) ? 1.0f : alpha[t];
    for (int h = 0; h < 2; ++h) {
        if (h == 1) __syncthreads();     // h=0 scatter readers of pwin/growF done
        for (int i = 0; i < 4; ++i) {
            int lv = tid + 1024 * i;               // within half
            int lvfull = h * 4096 + lv;
            int v = vblk * 8192 + lvfull;
            float post;
            if (mode == 1) {
                post = llr[v];
            } else {
                uint32_t n0 = nwin[3 * lvfull], n1 = nwin[3 * lvfull + 1], n2 = nwin[3 * lvfull + 2];
                float c0 = (n0 & 8u) ? -tl[n0 & 7u] : tl[n0 & 7u];
                float c1 = (n1 & 8u) ? -tl[n1 & 7u] : tl[n1 & 7u];
                float c2 = (n2 & 8u) ? -tl[n2 & 7u] : tl[n2 & 7u];
                post = llr[v] + ((c0 + c1) + c2);  // reference summation order
            }
            pwin[lv] = post;
            if (mode == 2) {
                out[v] = (post < 0.0f) ? 1.0f : 0.0f;
                out[NV + v] = post;
                if (v == 0) out[2 * NV] = 10.0f;
            }
        }
        if (mode == 2) continue;
        const int g = 2 * vblk + h;
        const int hb3 = h * 12288;       // nwin base for this half (3*lvfull = hb3 + 3*lvq + sl)
        if (tid < FBK) growF[tid] = goffF[(size_t)g * FBK + tid];
        __syncthreads();
        const size_t gb = (size_t)g * GSEG;
        for (int k = 0; k < 3; ++k) {
            int j0 = (tid + 1024 * k) * 4;
            const ushort4 lv4 = *(const ushort4*)&lvF[gb + j0];
            const ushort4 b4 = *(const ushort4*)&bidxF[gb + j0];
            float v0, v1, v2, v3;
            if (mode == 1) {
                v0 = pwin[lv4.x >> 2]; v1 = pwin[lv4.y >> 2];
                v2 = pwin[lv4.z >> 2]; v3 = pwin[lv4.w >> 2];
            } else {
                uint32_t e, lvq, nib; float c;
                e = lv4.x; lvq = e >> 2; nib = nwin[hb3 + 3 * lvq + (e & 3u)];
                c = (nib & 8u) ? -tl[nib & 7u] : tl[nib & 7u];
                v0 = a * (pwin[lvq] - c);
                e = lv4.y; lvq = e >> 2; nib = nwin[hb3 + 3 * lvq + (e & 3u)];
                c = (nib & 8u) ? -tl[nib & 7u] : tl[nib & 7u];
                v1 = a * (pwin[lvq] - c);
                e = lv4.z; lvq = e >> 2; nib = nwin[hb3 + 3 * lvq + (e & 3u)];
                c = (nib & 8u) ? -tl[nib & 7u] : tl[nib & 7u];
                v2 = a * (pwin[lvq] - c);
                e = lv4.w; lvq = e >> 2; nib = nwin[hb3 + 3 * lvq + (e & 3u)];
                c = (nib & 8u) ? -tl[nib & 7u] : tl[nib & 7u];
                v3 = a * (pwin[lvq] - c);
            }
            finterm[growF[b4.x] + j0 + 0] = v0;
            finterm[growF[b4.y] + j0 + 1] = v1;
            finterm[growF[b4.z] + j0 + 2] = v2;
            finterm[growF[b4.w] + j0 + 3] = v3;
        }
        __syncthreads();
    }
}

extern "C" void kernel_launch(void* const* d_in, const int* in_sizes, int n_in,
                              void* d_out, int out_size, void* d_ws, size_t ws_size,
                              hipStream_t stream) {
    const float* llr        = (const float*)d_in[0];
    const int*   var_idx    = (const int*)d_in[1];   (void)var_idx;   // implicit e/3
    const int*   chk_idx    = (const int*)d_in[2];
    const float* beta       = (const float*)d_in[3];
    const float* alpha      = (const float*)d_in[4];
    const float* thresholds = (const float*)d_in[5];
    float* out = (float*)d_out;

    // workspace layout (im2 aliases im1 — im1 dead after place1)
    char* wsb = (char*)d_ws;
    float*    finterm   = (float*)(wsb + 0);                  // 25165824
    uint16_t* f2pos     = (uint16_t*)(wsb + 25165824);        // 12582912
    uint16_t* lvF       = (uint16_t*)(wsb + 37748736);        // 12582912
    uint16_t* bidxF     = (uint16_t*)(wsb + 50331648);        // 12582912
    uint16_t* lposB     = (uint16_t*)(wsb + 62914560);        // 12582912
    uint16_t* b2pos     = (uint16_t*)(wsb + 75497472);        // 12582912
    uint8_t*  bidxB     = (uint8_t*)(wsb + 88080384);         // 6291456
    uint8_t*  binterm   = (uint8_t*)(wsb + 94371840);         // 6291456
    uint32_t* chk_edges = (uint32_t*)(wsb + 104857600);       // 25165824
    uint32_t* dest      = (uint32_t*)(wsb + 130023424);       // 25165824
    uint32_t* im1_e     = (uint32_t*)(wsb + 155189248);       // 25165824
    uint16_t* im1_c     = (uint16_t*)(wsb + 180355072);       // 12582912
    uint32_t* im2_pay   = im1_e;                              // alias (im1 dead)
    uint16_t* im2_el    = im1_c;                              // alias
    uint8_t*  f1rank    = (uint8_t*)(wsb + 192937984);        // 6291456
    uint8_t*  b1rank    = (uint8_t*)(wsb + 199229440);        // 6291456
    uint32_t* runcntF   = (uint32_t*)(wsb + 205520896);       // 1048576
    uint32_t* f1base    = (uint32_t*)(wsb + 206569472);       // 1048576
    uint32_t* runcntB   = (uint32_t*)(wsb + 207618048);       // 524288
    uint32_t* b1base    = (uint32_t*)(wsb + 208142336);       // 524288
    uint32_t* goffF     = (uint32_t*)(wsb + 208666624);       // 1048576
    uint32_t* goffB     = (uint32_t*)(wsb + 209715200);       // 524288
    uint32_t* gcur      = (uint32_t*)(wsb + 210239488);       // 4096
    uint32_t* gcurA     = gcur;
    uint32_t* gcurB     = gcur + 512;

    initcur_kernel<<<2, 512, 0, stream>>>(gcur);
    bin1_kernel<<<NBLK, 512, 0, stream>>>(chk_idx, gcurA, im1_e, im1_c);
    place1_kernel<<<FBK, 1024, 0, stream>>>(im1_e, im1_c, chk_edges, b1rank, runcntB);
    bin2_kernel<<<NBLK, 512, 0, stream>>>(chk_edges, gcurB, im2_pay, im2_el);
    place2_kernel<<<FG, 1024, 0, stream>>>(im2_pay, im2_el, dest, f1rank, runcntF);
    scanF_kernel<<<FBK, 256, 0, stream>>>(runcntF, f1base);
    fb_kernel<<<FG, 1024, 0, stream>>>(dest, f1rank, runcntF, f1base, goffF, f2pos, bidxF, lvF);
    scanB_kernel<<<VBK, 256, 0, stream>>>(runcntB, b1base);
    bb_kernel<<<FBK, 1024, 0, stream>>>(chk_edges, b1rank, runcntB, b1base, goffB, b2pos, bidxB, lposB);
    // seed: finterm <- llr (v2c_0) via forward permute (mode 1)
    var_kernel<<<VBK, 1024, 0, stream>>>(llr, binterm, b2pos, lvF, bidxF, goffF,
                                         finterm, thresholds, alpha, 0, 1, out);

    for (int t = 0; t < TT; ++t) {
        check_kernel<<<FBK, 1024, 0, stream>>>(finterm, f2pos, lposB, bidxB, goffB,
                                               binterm, beta, thresholds, t);
        var_kernel<<<VBK, 1024, 0, stream>>>(llr, binterm, b2pos, lvF, bidxF, goffF,
                                             finterm, thresholds, alpha, t,
                                             (t == TT - 1) ? 2 : 0, out);
    }
}